// Round 11
// baseline (641.749 us; speedup 1.0000x reference)
//
#include <hip/hip_runtime.h>

#define BB 16
#define DD 512
#define TT 4096
#define KK 1024
#define NN (BB*TT)              // 65536 rows
#define ROWS 64                 // k1: t-rows per tile
#define BT1 512                 // k1: 8 waves
#define NW1 8
#define MARGIN 1e-3f            // candidate margin (req <=8e-4, 25% slack)
#define CM 6                    // candidate slots per row (6 x 10 bits in u64)
// k2 geometry
#define ROWS2 16
#define BT2 256
#define XLD2 516                // floats per x row: 2064 B
#define PMH 64                  // replay pairs per half
#define NBLK2 (NN/ROWS2)        // 4096

typedef __attribute__((ext_vector_type(8))) short short8v;   // 8 bf16
typedef __attribute__((ext_vector_type(4))) float f32x4;

// ---- bf16 helper (RNE) ----
__device__ __forceinline__ unsigned short f2bf(float f) {
    unsigned int u = __float_as_uint(f);
    unsigned int r = (u + 0x7fffu + ((u >> 16) & 1u)) >> 16;
    return (unsigned short)r;
}

// ---- numpy pairwise-sum replication (fp32, squares) — verified passing ----
__device__ __forceinline__ float pw128_sq_strided(const float* a, int stride) {
    float V[16];
    #pragma unroll
    for (int l = 0; l < 16; ++l) {
        float q[8];
        #pragma unroll
        for (int k = 0; k < 8; ++k) {
            float e = a[(l + 16 * k) * stride];
            q[k] = __fmul_rn(e, e);
        }
        V[l] = __fadd_rn(__fadd_rn(__fadd_rn(q[0], q[1]), __fadd_rn(q[2], q[3])),
                         __fadd_rn(__fadd_rn(q[4], q[5]), __fadd_rn(q[6], q[7])));
    }
    float u[8];
    #pragma unroll
    for (int l = 0; l < 8; ++l) u[l] = __fadd_rn(V[l], V[l + 8]);
    float v[4];
    #pragma unroll
    for (int l = 0; l < 4; ++l) v[l] = __fadd_rn(u[l], u[l + 4]);
    return __fadd_rn(__fadd_rn(v[0], v[2]), __fadd_rn(v[1], v[3]));
}
__device__ __forceinline__ float pw512_sq_strided(const float* a, int stride) {
    float p0 = pw128_sq_strided(a, stride);
    float p1 = pw128_sq_strided(a + 128 * stride, stride);
    float p2 = pw128_sq_strided(a + 256 * stride, stride);
    float p3 = pw128_sq_strided(a + 384 * stride, stride);
    return __fadd_rn(__fadd_rn(p0, p1), __fadd_rn(p2, p3));
}

// ---------------- exact ||e||^2 per code row ----------------
__global__ void enorms_exact(const float* __restrict__ E, float* __restrict__ se) {
    int i = blockIdx.x * blockDim.x + threadIdx.x;
    if (i < KK) se[i] = pw512_sq_strided(E + (long)i * DD, 1);
}

// ---------------- pack E (hi bf16) into MFMA B-fragment layout (u32 pairs) --
__global__ void pack_e(const float* __restrict__ E, unsigned short* __restrict__ Bph) {
    int i = blockIdx.x * blockDim.x + threadIdx.x;   // 0 .. KK*DD/2-1
    if (i >= KK * DD / 2) return;
    int c = i >> 8;
    int k = (i & 255) * 2;                           // even k; k,k+1 share 8-group
    float2 v = *reinterpret_cast<const float2*>(E + ((long)c << 9) + k);
    int lane = (c & 15) + ((k >> 3) & 3) * 16;
    int hw = (((c >> 4) * 16 + (k >> 5)) * 64 + lane) * 8 + (k & 7);
    unsigned int pk = (unsigned int)f2bf(v.x) | ((unsigned int)f2bf(v.y) << 16);
    *reinterpret_cast<unsigned int*>(Bph + hw) = pk;
}

// =============== k1: MFMA filter, 8 waves, 2 blocks/CU ===============
__global__ __launch_bounds__(BT1, 4)
void vq_filter(const float* __restrict__ x,
               const unsigned short* __restrict__ Bph,
               const float* __restrict__ se,
               unsigned long long* __restrict__ cands) {
    __shared__ __align__(16) unsigned short Ahi[ROWS * DD];  // 64 KB, fragment layout
    __shared__ float wrowmin[NW1 * ROWS];                    // 2 KB
    __shared__ float gthr[ROWS];
    __shared__ int   rcnt[ROWS];
    __shared__ unsigned short rc[ROWS][CM];

    const int tid  = threadIdx.x;
    const int w    = tid >> 6;              // 0..7
    const int lane = tid & 63;
    const int blk  = blockIdx.x;
    const int b    = blk >> 6;
    const int t0   = (blk & 63) * ROWS;
    const long nbase = (long)b * TT + t0;
    const float* xb = x + (long)b * DD * TT + t0;

    if (tid < ROWS) {
        rcnt[tid] = 0;
        #pragma unroll
        for (int i = 0; i < CM; ++i) rc[tid][i] = 0;
    }

    // ---- stage x tile -> bf16-hi A fragments (8 its x 8 waves cover d) ----
    {
        const float* xbl = xb + lane;
        #pragma unroll
        for (int it = 0; it < 8; ++it) {
            int d0 = (it * NW1 + w) * 8;
            float v[8];
            #pragma unroll
            for (int jj = 0; jj < 8; ++jj)
                v[jj] = xbl[(long)(d0 + jj) * TT];
            union { short8v s; unsigned short h[8]; } hv;
            #pragma unroll
            for (int jj = 0; jj < 8; ++jj) hv.h[jj] = f2bf(v[jj]);
            int kk = d0 >> 5, lg = (d0 >> 3) & 3;
            int m = lane >> 4, lp = (lane & 15) + lg * 16;
            *(short8v*)(Ahi + (size_t)((m * 16 + kk) * 64 + lp) * 8) = hv.s;
        }
    }
    __syncthreads();

    // ---- GEMM: wave owns 128 codes (8 n-tiles), all 4 m-tiles, K=512 ----
    f32x4 acc[4][8];
    #pragma unroll
    for (int m = 0; m < 4; ++m)
        #pragma unroll
        for (int n = 0; n < 8; ++n)
            acc[m][n] = (f32x4){0.f, 0.f, 0.f, 0.f};

    const short8v* Bhv = (const short8v*)Bph;
    for (int kk = 0; kk < 16; ++kk) {
        short8v bh[8];
        #pragma unroll
        for (int n = 0; n < 8; ++n)
            bh[n] = Bhv[((w * 8 + n) * 16 + kk) * 64 + lane];
        short8v ah[4];
        #pragma unroll
        for (int m = 0; m < 4; ++m)
            ah[m] = *(const short8v*)&Ahi[((size_t)((m * 16 + kk) * 64 + lane)) * 8];
        #pragma unroll
        for (int n = 0; n < 8; ++n)
            #pragma unroll
            for (int m = 0; m < 4; ++m)
                acc[m][n] = __builtin_amdgcn_mfma_f32_16x16x32_bf16(ah[m], bh[n], acc[m][n], 0, 0, 0);
    }

    // ---- per-row wave-min (C/D: col=lane&15, row=(lane>>4)*4+reg) ----
    float sef[8];
    #pragma unroll
    for (int n = 0; n < 8; ++n) sef[n] = se[w * 128 + n * 16 + (lane & 15)];

    #pragma unroll
    for (int m = 0; m < 4; ++m) {
        #pragma unroll
        for (int r4 = 0; r4 < 4; ++r4) {
            float mn = 1e30f;
            #pragma unroll
            for (int n = 0; n < 8; ++n)
                mn = fminf(mn, fmaf(-2.f, acc[m][n][r4], sef[n]));
            #pragma unroll
            for (int off = 1; off < 16; off <<= 1)
                mn = fminf(mn, __shfl_xor(mn, off, 64));
            if ((lane & 15) == 0)
                wrowmin[w * ROWS + m * 16 + (lane >> 4) * 4 + r4] = mn;
        }
    }
    __syncthreads();

    if (tid < ROWS) {
        float g = 1e30f;
        #pragma unroll
        for (int ww = 0; ww < NW1; ++ww)
            g = fminf(g, wrowmin[ww * ROWS + tid]);
        gthr[tid] = g + MARGIN;
    }
    __syncthreads();

    // ---- push candidates within margin into per-row slots ----
    #pragma unroll
    for (int m = 0; m < 4; ++m) {
        #pragma unroll
        for (int r4 = 0; r4 < 4; ++r4) {
            int row = m * 16 + (lane >> 4) * 4 + r4;
            float th = gthr[row];
            #pragma unroll
            for (int n = 0; n < 8; ++n) {
                float sc = fmaf(-2.f, acc[m][n][r4], sef[n]);
                if (sc <= th) {
                    int pos = atomicAdd(&rcnt[row], 1);
                    if (pos < CM)
                        rc[row][pos] = (unsigned short)(w * 128 + n * 16 + (lane & 15));
                }
            }
        }
    }
    __syncthreads();

    if (tid < ROWS) {
        unsigned int cnt = (unsigned int)rcnt[tid];
        if (cnt > 15u) cnt = 15u;
        unsigned long long cw = cnt;
        #pragma unroll
        for (int i = 0; i < CM; ++i)
            cw |= (unsigned long long)(rc[tid][i] & 0x3ffu) << (4 + 10 * i);
        cands[nbase + tid] = cw;
    }
}

// =============== k2: half-tile pipelined replay + gather/loss/st ==========
__global__ __launch_bounds__(BT2, 4)
void vq_out(const float* __restrict__ x, const float* __restrict__ E,
            const float* __restrict__ se,
            const unsigned long long* __restrict__ cands,
            double* __restrict__ partials, float* __restrict__ out) {
    __shared__ __align__(16) float xsf[ROWS2 * XLD2];   // 33 KB
    __shared__ float sxs[ROWS2];
    __shared__ int   prw[2][PMH];
    __shared__ int   pcd[2][PMH];
    __shared__ unsigned long long rmin[ROWS2];
    __shared__ int   pcnt[2];
    __shared__ int   oany;
    __shared__ int   fidx[ROWS2];
    __shared__ int   oflag[ROWS2];
    __shared__ float owv[4];
    __shared__ int   owi[4];
    __shared__ double wloss[4];

    const int tid  = threadIdx.x;
    const int w    = tid >> 6;
    const int lane = tid & 63;
    const int blk  = blockIdx.x;
    const int b    = blk >> 8;
    const int t0   = (blk & 255) * ROWS2;
    const long nbase = (long)b * TT + t0;
    const float* xb = x + (long)b * DD * TT + t0;

    // ---- decode (wave 0; in-wave program order makes init safe) ----
    if (tid == 0) { pcnt[0] = 0; pcnt[1] = 0; oany = 0; }
    if (tid < ROWS2) {
        rmin[tid] = ~0ull;
        unsigned long long cw = cands[nbase + tid];
        int cnt = (int)(cw & 15u);
        oflag[tid] = 0;
        if (cnt == 1) {
            fidx[tid] = (int)((cw >> 4) & 0x3ffu);
        } else if (cnt >= 2 && cnt <= CM) {
            fidx[tid] = -1;
            int h = tid >> 3;
            int base = atomicAdd(&pcnt[h], cnt);
            for (int i = 0; i < cnt; ++i) {
                prw[h][base + i] = tid;
                pcd[h][base + i] = (int)((cw >> (4 + 10 * i)) & 0x3ffu);
            }
        } else {
            fidx[tid] = -1; oflag[tid] = 1;
            atomicOr(&oany, 1 << (tid >> 3));
        }
    }

    // ---- T14: issue ALL global loads up front (h0 then h1), write h0 ----
    float4 ra[4], rb[4];
    #pragma unroll
    for (int it = 0; it < 4; ++it) {
        int flat = it * BT2 + tid;          // 1024 float4 per half
        int d = flat >> 1, r4 = (flat & 1) * 4;
        ra[it] = *reinterpret_cast<const float4*>(xb + (long)d * TT + r4);
    }
    #pragma unroll
    for (int it = 0; it < 4; ++it) {
        int flat = it * BT2 + tid;
        int d = flat >> 1, r4 = (flat & 1) * 4 + 8;
        rb[it] = *reinterpret_cast<const float4*>(xb + (long)d * TT + r4);
    }
    #pragma unroll
    for (int it = 0; it < 4; ++it) {
        int flat = it * BT2 + tid;
        int d = flat >> 1, r4 = (flat & 1) * 4;
        xsf[(r4 + 0) * XLD2 + d] = ra[it].x;
        xsf[(r4 + 1) * XLD2 + d] = ra[it].y;
        xsf[(r4 + 2) * XLD2 + d] = ra[it].z;
        xsf[(r4 + 3) * XLD2 + d] = ra[it].w;
    }
    __syncthreads();                        // B1: h0 + decode ready

    // ---- pw h0: 16 threads/row, exact numpy tree via width-16 butterfly ----
    if (tid < 128) {
        int r = tid >> 4, l = tid & 15;
        const float* bp = xsf + r * XLD2;
        float pblk[4];
        #pragma unroll
        for (int kb = 0; kb < 4; ++kb) {
            float q[8];
            #pragma unroll
            for (int k = 0; k < 8; ++k) {
                float e = bp[kb * 128 + l + 16 * k];
                q[k] = __fmul_rn(e, e);
            }
            float V = __fadd_rn(__fadd_rn(__fadd_rn(q[0], q[1]), __fadd_rn(q[2], q[3])),
                                __fadd_rn(__fadd_rn(q[4], q[5]), __fadd_rn(q[6], q[7])));
            V = __fadd_rn(V, __shfl_xor(V, 8, 16));   // commutes: bit-identical tree
            V = __fadd_rn(V, __shfl_xor(V, 4, 16));
            V = __fadd_rn(V, __shfl_xor(V, 2, 16));
            V = __fadd_rn(V, __shfl_xor(V, 1, 16));
            pblk[kb] = V;
        }
        if (l == 0)
            sxs[r] = __fadd_rn(__fadd_rn(pblk[0], pblk[1]), __fadd_rn(pblk[2], pblk[3]));
    }
    __syncthreads();                        // B2: sxs h0

    // ---- replay h0 (waves 2-3), fused argmin via LDS atomicMin ----
    {
        int np = pcnt[0] < PMH ? pcnt[0] : PMH;
        int pi = tid - 128;
        if (pi >= 0 && pi < np) {
            int r = prw[0][pi], c = pcd[0][pi];
            const float4* Ep4 = reinterpret_cast<const float4*>(E + (long)c * DD);
            const float4* Xp4 = reinterpret_cast<const float4*>(xsf + r * XLD2);
            float g = 0.f;
            #pragma unroll 4
            for (int jj = 0; jj < 128; ++jj) {
                float4 e4 = Ep4[jj], x4 = Xp4[jj];
                g = __fmaf_rn(x4.x, e4.x, g);
                g = __fmaf_rn(x4.y, e4.y, g);
                g = __fmaf_rn(x4.z, e4.z, g);
                g = __fmaf_rn(x4.w, e4.w, g);
            }
            float t1 = __fadd_rn(sxs[r], se[c]);
            float d  = __fsub_rn(t1, __fmul_rn(2.f, g));
            unsigned int bb = __float_as_uint(d);
            unsigned int u  = (bb & 0x80000000u) ? ~bb : (bb | 0x80000000u);
            atomicMin(&rmin[r], ((unsigned long long)u << 10) | (unsigned int)c);
        }
    }
    __syncthreads();                        // B3: rmin h0
    if (tid < 8 && fidx[tid] < 0 && !oflag[tid])
        fidx[tid] = (int)(rmin[tid] & 0x3ffu);

    // ---- overflow h0 (rare, uniform branch) ----
    if (oany & 1) {
        for (int r = 0; r < 8; ++r) {
            if (!oflag[r]) continue;
            const float4* Xp4 = reinterpret_cast<const float4*>(xsf + r * XLD2);
            float bd = 1e30f; int bi = KK;
            for (int q = 0; q < 4; ++q) {
                int c = q * BT2 + tid;
                const float4* Ep4 = reinterpret_cast<const float4*>(E + (long)c * DD);
                float g = 0.f;
                #pragma unroll 4
                for (int jj = 0; jj < 128; ++jj) {
                    float4 e4 = Ep4[jj], x4 = Xp4[jj];
                    g = __fmaf_rn(x4.x, e4.x, g);
                    g = __fmaf_rn(x4.y, e4.y, g);
                    g = __fmaf_rn(x4.z, e4.z, g);
                    g = __fmaf_rn(x4.w, e4.w, g);
                }
                float d = __fsub_rn(__fadd_rn(sxs[r], se[c]), __fmul_rn(2.f, g));
                if (d < bd) { bd = d; bi = c; }
            }
            #pragma unroll
            for (int off = 32; off; off >>= 1) {
                float tv = __shfl_down(bd, off, 64);
                int   ti = __shfl_down(bi, off, 64);
                if (tv < bd || (tv == bd && ti < bi)) { bd = tv; bi = ti; }
            }
            if (lane == 0) { owv[w] = bd; owi[w] = bi; }
            __syncthreads();
            if (tid == 0) {
                float BD = 1e30f; int BI = KK;
                #pragma unroll
                for (int ww = 0; ww < 4; ++ww)
                    if (owv[ww] < BD || (owv[ww] == BD && owi[ww] < BI)) { BD = owv[ww]; BI = owi[ww]; }
                fidx[r] = BI;
            }
            __syncthreads();
        }
    }

    // ---- write h1 to LDS (loads landed during h0 processing) ----
    #pragma unroll
    for (int it = 0; it < 4; ++it) {
        int flat = it * BT2 + tid;
        int d = flat >> 1, r4 = (flat & 1) * 4 + 8;
        xsf[(r4 + 0) * XLD2 + d] = rb[it].x;
        xsf[(r4 + 1) * XLD2 + d] = rb[it].y;
        xsf[(r4 + 2) * XLD2 + d] = rb[it].z;
        xsf[(r4 + 3) * XLD2 + d] = rb[it].w;
    }
    __syncthreads();                        // B4: h1 ready + fidx h0 final

    // ---- gather h0 (overlaps pw h1 in program order) ----
    double lacc = 0.0;
    #pragma unroll
    for (int it = 0; it < 4; ++it) {
        int flat = it * BT2 + tid;          // 1024 f4 = rows 0..7
        int r = flat >> 7;
        int j = (flat & 127) * 4;
        int idx = fidx[r];
        float4 ev = *reinterpret_cast<const float4*>(E + (long)idx * DD + j);
        float4 xv = *reinterpret_cast<const float4*>(&xsf[r * XLD2 + j]);
        float d0 = __fsub_rn(ev.x, xv.x);
        float d1 = __fsub_rn(ev.y, xv.y);
        float d2 = __fsub_rn(ev.z, xv.z);
        float d3 = __fsub_rn(ev.w, xv.w);
        float4 st;
        st.x = __fadd_rn(xv.x, d0); st.y = __fadd_rn(xv.y, d1);
        st.z = __fadd_rn(xv.z, d2); st.w = __fadd_rn(xv.w, d3);
        *reinterpret_cast<float4*>(out + (size_t)(nbase + r) * DD + j) = st;
        lacc += (double)d0 * d0 + (double)d1 * d1 + (double)d2 * d2 + (double)d3 * d3;
    }

    // ---- pw h1 ----
    if (tid < 128) {
        int r = 8 + (tid >> 4), l = tid & 15;
        const float* bp = xsf + r * XLD2;
        float pblk[4];
        #pragma unroll
        for (int kb = 0; kb < 4; ++kb) {
            float q[8];
            #pragma unroll
            for (int k = 0; k < 8; ++k) {
                float e = bp[kb * 128 + l + 16 * k];
                q[k] = __fmul_rn(e, e);
            }
            float V = __fadd_rn(__fadd_rn(__fadd_rn(q[0], q[1]), __fadd_rn(q[2], q[3])),
                                __fadd_rn(__fadd_rn(q[4], q[5]), __fadd_rn(q[6], q[7])));
            V = __fadd_rn(V, __shfl_xor(V, 8, 16));
            V = __fadd_rn(V, __shfl_xor(V, 4, 16));
            V = __fadd_rn(V, __shfl_xor(V, 2, 16));
            V = __fadd_rn(V, __shfl_xor(V, 1, 16));
            pblk[kb] = V;
        }
        if (l == 0)
            sxs[r] = __fadd_rn(__fadd_rn(pblk[0], pblk[1]), __fadd_rn(pblk[2], pblk[3]));
    }
    __syncthreads();                        // B5: sxs h1

    // ---- replay h1 (waves 2-3) ----
    {
        int np = pcnt[1] < PMH ? pcnt[1] : PMH;
        int pi = tid - 128;
        if (pi >= 0 && pi < np) {
            int r = prw[1][pi], c = pcd[1][pi];
            const float4* Ep4 = reinterpret_cast<const float4*>(E + (long)c * DD);
            const float4* Xp4 = reinterpret_cast<const float4*>(xsf + r * XLD2);
            float g = 0.f;
            #pragma unroll 4
            for (int jj = 0; jj < 128; ++jj) {
                float4 e4 = Ep4[jj], x4 = Xp4[jj];
                g = __fmaf_rn(x4.x, e4.x, g);
                g = __fmaf_rn(x4.y, e4.y, g);
                g = __fmaf_rn(x4.z, e4.z, g);
                g = __fmaf_rn(x4.w, e4.w, g);
            }
            float t1 = __fadd_rn(sxs[r], se[c]);
            float d  = __fsub_rn(t1, __fmul_rn(2.f, g));
            unsigned int bb = __float_as_uint(d);
            unsigned int u  = (bb & 0x80000000u) ? ~bb : (bb | 0x80000000u);
            atomicMin(&rmin[r], ((unsigned long long)u << 10) | (unsigned int)c);
        }
    }
    __syncthreads();                        // B6: rmin h1
    if (tid >= 8 && tid < 16 && fidx[tid] < 0 && !oflag[tid])
        fidx[tid] = (int)(rmin[tid] & 0x3ffu);

    // ---- overflow h1 (rare) ----
    if (oany & 2) {
        for (int r = 8; r < 16; ++r) {
            if (!oflag[r]) continue;
            const float4* Xp4 = reinterpret_cast<const float4*>(xsf + r * XLD2);
            float bd = 1e30f; int bi = KK;
            for (int q = 0; q < 4; ++q) {
                int c = q * BT2 + tid;
                const float4* Ep4 = reinterpret_cast<const float4*>(E + (long)c * DD);
                float g = 0.f;
                #pragma unroll 4
                for (int jj = 0; jj < 128; ++jj) {
                    float4 e4 = Ep4[jj], x4 = Xp4[jj];
                    g = __fmaf_rn(x4.x, e4.x, g);
                    g = __fmaf_rn(x4.y, e4.y, g);
                    g = __fmaf_rn(x4.z, e4.z, g);
                    g = __fmaf_rn(x4.w, e4.w, g);
                }
                float d = __fsub_rn(__fadd_rn(sxs[r], se[c]), __fmul_rn(2.f, g));
                if (d < bd) { bd = d; bi = c; }
            }
            #pragma unroll
            for (int off = 32; off; off >>= 1) {
                float tv = __shfl_down(bd, off, 64);
                int   ti = __shfl_down(bi, off, 64);
                if (tv < bd || (tv == bd && ti < bi)) { bd = tv; bi = ti; }
            }
            if (lane == 0) { owv[w] = bd; owi[w] = bi; }
            __syncthreads();
            if (tid == 0) {
                float BD = 1e30f; int BI = KK;
                #pragma unroll
                for (int ww = 0; ww < 4; ++ww)
                    if (owv[ww] < BD || (owv[ww] == BD && owi[ww] < BI)) { BD = owv[ww]; BI = owi[ww]; }
                fidx[r] = BI;
            }
            __syncthreads();
        }
    }
    __syncthreads();                        // B7: fidx h1 final

    if (tid < ROWS2)
        out[(size_t)NN * DD + 1 + nbase + tid] = (float)fidx[tid];

    // ---- gather h1 ----
    #pragma unroll
    for (int it = 0; it < 4; ++it) {
        int flat = it * BT2 + tid;
        int r = 8 + (flat >> 7);
        int j = (flat & 127) * 4;
        int idx = fidx[r];
        float4 ev = *reinterpret_cast<const float4*>(E + (long)idx * DD + j);
        float4 xv = *reinterpret_cast<const float4*>(&xsf[r * XLD2 + j]);
        float d0 = __fsub_rn(ev.x, xv.x);
        float d1 = __fsub_rn(ev.y, xv.y);
        float d2 = __fsub_rn(ev.z, xv.z);
        float d3 = __fsub_rn(ev.w, xv.w);
        float4 st;
        st.x = __fadd_rn(xv.x, d0); st.y = __fadd_rn(xv.y, d1);
        st.z = __fadd_rn(xv.z, d2); st.w = __fadd_rn(xv.w, d3);
        *reinterpret_cast<float4*>(out + (size_t)(nbase + r) * DD + j) = st;
        lacc += (double)d0 * d0 + (double)d1 * d1 + (double)d2 * d2 + (double)d3 * d3;
    }
    #pragma unroll
    for (int off = 32; off; off >>= 1) lacc += __shfl_down(lacc, off, 64);
    if (lane == 0) wloss[w] = lacc;
    __syncthreads();
    if (tid == 0)
        partials[blk] = wloss[0] + wloss[1] + wloss[2] + wloss[3];
}

// ---------------- loss finalize: sum 4096 block partials ----------------
__global__ void finalize_kernel(const double* __restrict__ partials, float* __restrict__ out) {
    __shared__ double sm[16];
    const int tid = threadIdx.x;                // 1024 threads
    const int w = tid >> 6, lane = tid & 63;
    double a = 0.0;
    #pragma unroll
    for (int i = 0; i < NBLK2 / 1024; ++i)
        a += partials[i * 1024 + tid];
    #pragma unroll
    for (int off = 32; off; off >>= 1) a += __shfl_down(a, off, 64);
    if (lane == 0) sm[w] = a;
    __syncthreads();
    if (tid == 0) {
        double s = 0.0;
        #pragma unroll
        for (int i = 0; i < 16; ++i) s += sm[i];
        out[(size_t)NN * DD] = (float)(1.25 * s / ((double)NN * DD));
    }
}

extern "C" void kernel_launch(void* const* d_in, const int* in_sizes, int n_in,
                              void* d_out, int out_size, void* d_ws, size_t ws_size,
                              hipStream_t stream) {
    const float* x = (const float*)d_in[0];
    const float* E = (const float*)d_in[1];
    float* out = (float*)d_out;
    double* partials = (double*)d_ws;                                       // 32 KB
    float* se = (float*)((char*)d_ws + 32768);                              // 4 KB
    unsigned short* Bph = (unsigned short*)((char*)d_ws + 65536);           // 1 MB
    unsigned long long* cands =
        (unsigned long long*)((char*)d_ws + 65536 + 1048576);               // 512 KB

    enorms_exact<<<4, 256, 0, stream>>>(E, se);
    pack_e<<<(KK * DD / 2) / 256, 256, 0, stream>>>(E, Bph);
    vq_filter<<<NN / ROWS, BT1, 0, stream>>>(x, Bph, se, cands);
    vq_out<<<NBLK2, BT2, 0, stream>>>(x, E, se, cands, partials, out);
    finalize_kernel<<<1, 1024, 0, stream>>>(partials, out);
}

// Round 12
// 267.680 us; speedup vs baseline: 2.3974x; 2.3974x over previous
//
#include <hip/hip_runtime.h>

#define BB 16
#define DD 512
#define TT 4096
#define KK 1024
#define NN (BB*TT)              // 65536 rows
#define ROWS 64                 // k1: t-rows per block
#define BLOCKT 1024             // k1: 16 waves
#define NWAVES 16
#define MARGIN 1e-3f            // candidate margin (req <=8e-4, 25% slack)
#define CM 6                    // candidate slots per row (6 x 10 bits in u64)
// k2 geometry
#define ROWS2 16
#define BT2 256
#define XLD2 516                // floats per x row: 2064 B
#define PMH 64                  // replay pairs per half
#define NBLK2 (NN/ROWS2)        // 4096

typedef __attribute__((ext_vector_type(8))) short short8v;   // 8 bf16
typedef __attribute__((ext_vector_type(4))) float f32x4;

// ---- bf16 helper (RNE) ----
__device__ __forceinline__ unsigned short f2bf(float f) {
    unsigned int u = __float_as_uint(f);
    unsigned int r = (u + 0x7fffu + ((u >> 16) & 1u)) >> 16;
    return (unsigned short)r;
}

// ---- numpy pairwise-sum replication (fp32, squares) — verified passing ----
__device__ __forceinline__ float pw128_sq_strided(const float* a, int stride) {
    float V[16];
    #pragma unroll
    for (int l = 0; l < 16; ++l) {
        float q[8];
        #pragma unroll
        for (int k = 0; k < 8; ++k) {
            float e = a[(l + 16 * k) * stride];
            q[k] = __fmul_rn(e, e);
        }
        V[l] = __fadd_rn(__fadd_rn(__fadd_rn(q[0], q[1]), __fadd_rn(q[2], q[3])),
                         __fadd_rn(__fadd_rn(q[4], q[5]), __fadd_rn(q[6], q[7])));
    }
    float u[8];
    #pragma unroll
    for (int l = 0; l < 8; ++l) u[l] = __fadd_rn(V[l], V[l + 8]);
    float v[4];
    #pragma unroll
    for (int l = 0; l < 4; ++l) v[l] = __fadd_rn(u[l], u[l + 4]);
    return __fadd_rn(__fadd_rn(v[0], v[2]), __fadd_rn(v[1], v[3]));
}
__device__ __forceinline__ float pw512_sq_strided(const float* a, int stride) {
    float p0 = pw128_sq_strided(a, stride);
    float p1 = pw128_sq_strided(a + 128 * stride, stride);
    float p2 = pw128_sq_strided(a + 256 * stride, stride);
    float p3 = pw128_sq_strided(a + 384 * stride, stride);
    return __fadd_rn(__fadd_rn(p0, p1), __fadd_rn(p2, p3));
}

// ---------------- exact ||e||^2 per code row ----------------
__global__ void enorms_exact(const float* __restrict__ E, float* __restrict__ se) {
    int i = blockIdx.x * blockDim.x + threadIdx.x;
    if (i < KK) se[i] = pw512_sq_strided(E + (long)i * DD, 1);
}

// ---------------- pack E (hi bf16) into MFMA B-fragment layout (u32 pairs) --
__global__ void pack_e(const float* __restrict__ E, unsigned short* __restrict__ Bph) {
    int i = blockIdx.x * blockDim.x + threadIdx.x;   // 0 .. KK*DD/2-1
    if (i >= KK * DD / 2) return;
    int c = i >> 8;
    int k = (i & 255) * 2;                           // even k; k,k+1 share 8-group
    float2 v = *reinterpret_cast<const float2*>(E + ((long)c << 9) + k);
    int lane = (c & 15) + ((k >> 3) & 3) * 16;
    int hw = (((c >> 4) * 16 + (k >> 5)) * 64 + lane) * 8 + (k & 7);
    unsigned int pk = (unsigned int)f2bf(v.x) | ((unsigned int)f2bf(v.y) << 16);
    *reinterpret_cast<unsigned int*>(Bph + hw) = pk;
}

// =============== k1: MFMA filter (r9-proven form) -> candidate lists ======
__global__ __launch_bounds__(BLOCKT)
void vq_filter(const float* __restrict__ x,
               const unsigned short* __restrict__ Bph,
               const float* __restrict__ se,
               unsigned long long* __restrict__ cands) {
    __shared__ __align__(16) unsigned short Ahi[ROWS * DD];  // 64 KB, fragment layout
    __shared__ float wrowmin[NWAVES * ROWS];
    __shared__ float gthr[ROWS];
    __shared__ int   rcnt[ROWS];
    __shared__ unsigned short rc[ROWS][CM];

    const int tid  = threadIdx.x;
    const int w    = tid >> 6;
    const int lane = tid & 63;
    const int blk  = blockIdx.x;
    const int b    = blk >> 6;
    const int t0   = (blk & 63) * ROWS;
    const long nbase = (long)b * TT + t0;
    const float* xb = x + (long)b * DD * TT + t0;

    if (tid < ROWS) {
        rcnt[tid] = 0;
        #pragma unroll
        for (int i = 0; i < CM; ++i) rc[tid][i] = 0;
    }

    // ---- stage x tile -> bf16-hi A fragments (coalesced loads, b128 writes) ----
    {
        const float* xbl = xb + lane;
        #pragma unroll
        for (int it = 0; it < 4; ++it) {
            int d0 = (it * NWAVES + w) * 8;
            float v[8];
            #pragma unroll
            for (int jj = 0; jj < 8; ++jj)
                v[jj] = xbl[(long)(d0 + jj) * TT];
            union { short8v s; unsigned short h[8]; } hv;
            #pragma unroll
            for (int jj = 0; jj < 8; ++jj) hv.h[jj] = f2bf(v[jj]);
            int kk = d0 >> 5, lg = (d0 >> 3) & 3;
            int m = lane >> 4, lp = (lane & 15) + lg * 16;
            *(short8v*)(Ahi + (size_t)((m * 16 + kk) * 64 + lp) * 8) = hv.s;
        }
    }
    __syncthreads();

    // ---- GEMM: wave owns 64 codes (4 n-tiles), all 4 m-tiles, K=512 ----
    f32x4 acc[4][4];
    #pragma unroll
    for (int m = 0; m < 4; ++m)
        #pragma unroll
        for (int n = 0; n < 4; ++n)
            acc[m][n] = (f32x4){0.f, 0.f, 0.f, 0.f};

    const short8v* Bhv = (const short8v*)Bph;
    for (int kk = 0; kk < 16; ++kk) {
        short8v bh[4];
        #pragma unroll
        for (int n = 0; n < 4; ++n)
            bh[n] = Bhv[((w * 4 + n) * 16 + kk) * 64 + lane];
        short8v ah[4];
        #pragma unroll
        for (int m = 0; m < 4; ++m)
            ah[m] = *(const short8v*)&Ahi[((size_t)((m * 16 + kk) * 64 + lane)) * 8];
        #pragma unroll
        for (int n = 0; n < 4; ++n)
            #pragma unroll
            for (int m = 0; m < 4; ++m)
                acc[m][n] = __builtin_amdgcn_mfma_f32_16x16x32_bf16(ah[m], bh[n], acc[m][n], 0, 0, 0);
    }

    // ---- per-row wave-min (C/D: col=lane&15, row=(lane>>4)*4+reg) ----
    float sef[4];
    #pragma unroll
    for (int n = 0; n < 4; ++n) sef[n] = se[w * 64 + n * 16 + (lane & 15)];

    #pragma unroll
    for (int m = 0; m < 4; ++m) {
        #pragma unroll
        for (int r4 = 0; r4 < 4; ++r4) {
            float mn = 1e30f;
            #pragma unroll
            for (int n = 0; n < 4; ++n)
                mn = fminf(mn, fmaf(-2.f, acc[m][n][r4], sef[n]));
            #pragma unroll
            for (int off = 1; off < 16; off <<= 1)
                mn = fminf(mn, __shfl_xor(mn, off, 64));
            if ((lane & 15) == 0)
                wrowmin[w * ROWS + m * 16 + (lane >> 4) * 4 + r4] = mn;
        }
    }
    __syncthreads();

    if (tid < ROWS) {
        float g = 1e30f;
        #pragma unroll
        for (int ww = 0; ww < NWAVES; ++ww)
            g = fminf(g, wrowmin[ww * ROWS + tid]);
        gthr[tid] = g + MARGIN;
    }
    __syncthreads();

    // ---- push candidates within margin into per-row slots ----
    #pragma unroll
    for (int m = 0; m < 4; ++m) {
        #pragma unroll
        for (int r4 = 0; r4 < 4; ++r4) {
            int row = m * 16 + (lane >> 4) * 4 + r4;
            float th = gthr[row];
            #pragma unroll
            for (int n = 0; n < 4; ++n) {
                float sc = fmaf(-2.f, acc[m][n][r4], sef[n]);
                if (sc <= th) {
                    int pos = atomicAdd(&rcnt[row], 1);
                    if (pos < CM)
                        rc[row][pos] = (unsigned short)(w * 64 + n * 16 + (lane & 15));
                }
            }
        }
    }
    __syncthreads();

    if (tid < ROWS) {
        unsigned int cnt = (unsigned int)rcnt[tid];
        if (cnt > 15u) cnt = 15u;
        unsigned long long cw = cnt;
        #pragma unroll
        for (int i = 0; i < CM; ++i)
            cw |= (unsigned long long)(rc[tid][i] & 0x3ffu) << (4 + 10 * i);
        cands[nbase + tid] = cw;
    }
}

// =============== k2: half-tile pipelined replay + gather/loss/st ==========
__global__ __launch_bounds__(BT2, 4)
void vq_out(const float* __restrict__ x, const float* __restrict__ E,
            const float* __restrict__ se,
            const unsigned long long* __restrict__ cands,
            double* __restrict__ partials, float* __restrict__ out) {
    __shared__ __align__(16) float xsf[ROWS2 * XLD2];   // 33 KB
    __shared__ float sxs[ROWS2];
    __shared__ int   prw[2][PMH];
    __shared__ int   pcd[2][PMH];
    __shared__ unsigned long long rmin[ROWS2];
    __shared__ int   pcnt[2];
    __shared__ int   oany;
    __shared__ int   fidx[ROWS2];
    __shared__ int   oflag[ROWS2];
    __shared__ float owv[4];
    __shared__ int   owi[4];
    __shared__ double wloss[4];

    const int tid  = threadIdx.x;
    const int w    = tid >> 6;
    const int lane = tid & 63;
    const int blk  = blockIdx.x;
    const int b    = blk >> 8;
    const int t0   = (blk & 255) * ROWS2;
    const long nbase = (long)b * TT + t0;
    const float* xb = x + (long)b * DD * TT + t0;

    // ---- decode (wave 0; in-wave program order makes init safe) ----
    if (tid == 0) { pcnt[0] = 0; pcnt[1] = 0; oany = 0; }
    if (tid < ROWS2) {
        rmin[tid] = ~0ull;
        unsigned long long cw = cands[nbase + tid];
        int cnt = (int)(cw & 15u);
        oflag[tid] = 0;
        if (cnt == 1) {
            fidx[tid] = (int)((cw >> 4) & 0x3ffu);
        } else if (cnt >= 2 && cnt <= CM) {
            fidx[tid] = -1;
            int h = tid >> 3;
            int base = atomicAdd(&pcnt[h], cnt);
            for (int i = 0; i < cnt; ++i) {
                prw[h][base + i] = tid;
                pcd[h][base + i] = (int)((cw >> (4 + 10 * i)) & 0x3ffu);
            }
        } else {
            fidx[tid] = -1; oflag[tid] = 1;
            atomicOr(&oany, 1 << (tid >> 3));
        }
    }

    // ---- T14: issue ALL global loads up front (h0 then h1), write h0 ----
    float4 ra[4], rb[4];
    #pragma unroll
    for (int it = 0; it < 4; ++it) {
        int flat = it * BT2 + tid;          // 1024 float4 per half
        int d = flat >> 1, r4 = (flat & 1) * 4;
        ra[it] = *reinterpret_cast<const float4*>(xb + (long)d * TT + r4);
    }
    #pragma unroll
    for (int it = 0; it < 4; ++it) {
        int flat = it * BT2 + tid;
        int d = flat >> 1, r4 = (flat & 1) * 4 + 8;
        rb[it] = *reinterpret_cast<const float4*>(xb + (long)d * TT + r4);
    }
    #pragma unroll
    for (int it = 0; it < 4; ++it) {
        int flat = it * BT2 + tid;
        int d = flat >> 1, r4 = (flat & 1) * 4;
        xsf[(r4 + 0) * XLD2 + d] = ra[it].x;
        xsf[(r4 + 1) * XLD2 + d] = ra[it].y;
        xsf[(r4 + 2) * XLD2 + d] = ra[it].z;
        xsf[(r4 + 3) * XLD2 + d] = ra[it].w;
    }
    __syncthreads();                        // B1: h0 + decode ready

    // ---- pw h0: 16 threads/row, exact numpy tree via width-16 butterfly ----
    if (tid < 128) {
        int r = tid >> 4, l = tid & 15;
        const float* bp = xsf + r * XLD2;
        float pblk[4];
        #pragma unroll
        for (int kb = 0; kb < 4; ++kb) {
            float q[8];
            #pragma unroll
            for (int k = 0; k < 8; ++k) {
                float e = bp[kb * 128 + l + 16 * k];
                q[k] = __fmul_rn(e, e);
            }
            float V = __fadd_rn(__fadd_rn(__fadd_rn(q[0], q[1]), __fadd_rn(q[2], q[3])),
                                __fadd_rn(__fadd_rn(q[4], q[5]), __fadd_rn(q[6], q[7])));
            V = __fadd_rn(V, __shfl_xor(V, 8, 16));   // commutes: bit-identical tree
            V = __fadd_rn(V, __shfl_xor(V, 4, 16));
            V = __fadd_rn(V, __shfl_xor(V, 2, 16));
            V = __fadd_rn(V, __shfl_xor(V, 1, 16));
            pblk[kb] = V;
        }
        if (l == 0)
            sxs[r] = __fadd_rn(__fadd_rn(pblk[0], pblk[1]), __fadd_rn(pblk[2], pblk[3]));
    }
    __syncthreads();                        // B2: sxs h0

    // ---- replay h0 (waves 2-3), fused argmin via LDS atomicMin ----
    {
        int np = pcnt[0] < PMH ? pcnt[0] : PMH;
        int pi = tid - 128;
        if (pi >= 0 && pi < np) {
            int r = prw[0][pi], c = pcd[0][pi];
            const float4* Ep4 = reinterpret_cast<const float4*>(E + (long)c * DD);
            const float4* Xp4 = reinterpret_cast<const float4*>(xsf + r * XLD2);
            float g = 0.f;
            #pragma unroll 4
            for (int jj = 0; jj < 128; ++jj) {
                float4 e4 = Ep4[jj], x4 = Xp4[jj];
                g = __fmaf_rn(x4.x, e4.x, g);
                g = __fmaf_rn(x4.y, e4.y, g);
                g = __fmaf_rn(x4.z, e4.z, g);
                g = __fmaf_rn(x4.w, e4.w, g);
            }
            float t1 = __fadd_rn(sxs[r], se[c]);
            float d  = __fsub_rn(t1, __fmul_rn(2.f, g));
            unsigned int bb = __float_as_uint(d);
            unsigned int u  = (bb & 0x80000000u) ? ~bb : (bb | 0x80000000u);
            atomicMin(&rmin[r], ((unsigned long long)u << 10) | (unsigned int)c);
        }
    }
    __syncthreads();                        // B3: rmin h0
    if (tid < 8 && fidx[tid] < 0 && !oflag[tid])
        fidx[tid] = (int)(rmin[tid] & 0x3ffu);

    // ---- overflow h0 (rare, uniform branch) ----
    if (oany & 1) {
        for (int r = 0; r < 8; ++r) {
            if (!oflag[r]) continue;
            const float4* Xp4 = reinterpret_cast<const float4*>(xsf + r * XLD2);
            float bd = 1e30f; int bi = KK;
            for (int q = 0; q < 4; ++q) {
                int c = q * BT2 + tid;
                const float4* Ep4 = reinterpret_cast<const float4*>(E + (long)c * DD);
                float g = 0.f;
                #pragma unroll 4
                for (int jj = 0; jj < 128; ++jj) {
                    float4 e4 = Ep4[jj], x4 = Xp4[jj];
                    g = __fmaf_rn(x4.x, e4.x, g);
                    g = __fmaf_rn(x4.y, e4.y, g);
                    g = __fmaf_rn(x4.z, e4.z, g);
                    g = __fmaf_rn(x4.w, e4.w, g);
                }
                float d = __fsub_rn(__fadd_rn(sxs[r], se[c]), __fmul_rn(2.f, g));
                if (d < bd) { bd = d; bi = c; }
            }
            #pragma unroll
            for (int off = 32; off; off >>= 1) {
                float tv = __shfl_down(bd, off, 64);
                int   ti = __shfl_down(bi, off, 64);
                if (tv < bd || (tv == bd && ti < bi)) { bd = tv; bi = ti; }
            }
            if (lane == 0) { owv[w] = bd; owi[w] = bi; }
            __syncthreads();
            if (tid == 0) {
                float BD = 1e30f; int BI = KK;
                #pragma unroll
                for (int ww = 0; ww < 4; ++ww)
                    if (owv[ww] < BD || (owv[ww] == BD && owi[ww] < BI)) { BD = owv[ww]; BI = owi[ww]; }
                fidx[r] = BI;
            }
            __syncthreads();
        }
    }

    // ---- write h1 to LDS (loads landed during h0 processing) ----
    #pragma unroll
    for (int it = 0; it < 4; ++it) {
        int flat = it * BT2 + tid;
        int d = flat >> 1, r4 = (flat & 1) * 4 + 8;
        xsf[(r4 + 0) * XLD2 + d] = rb[it].x;
        xsf[(r4 + 1) * XLD2 + d] = rb[it].y;
        xsf[(r4 + 2) * XLD2 + d] = rb[it].z;
        xsf[(r4 + 3) * XLD2 + d] = rb[it].w;
    }
    __syncthreads();                        // B4: h1 ready + fidx h0 final

    // ---- gather h0 (overlaps pw h1 in program order) ----
    double lacc = 0.0;
    #pragma unroll
    for (int it = 0; it < 4; ++it) {
        int flat = it * BT2 + tid;          // 1024 f4 = rows 0..7
        int r = flat >> 7;
        int j = (flat & 127) * 4;
        int idx = fidx[r];
        float4 ev = *reinterpret_cast<const float4*>(E + (long)idx * DD + j);
        float4 xv = *reinterpret_cast<const float4*>(&xsf[r * XLD2 + j]);
        float d0 = __fsub_rn(ev.x, xv.x);
        float d1 = __fsub_rn(ev.y, xv.y);
        float d2 = __fsub_rn(ev.z, xv.z);
        float d3 = __fsub_rn(ev.w, xv.w);
        float4 st;
        st.x = __fadd_rn(xv.x, d0); st.y = __fadd_rn(xv.y, d1);
        st.z = __fadd_rn(xv.z, d2); st.w = __fadd_rn(xv.w, d3);
        *reinterpret_cast<float4*>(out + (size_t)(nbase + r) * DD + j) = st;
        lacc += (double)d0 * d0 + (double)d1 * d1 + (double)d2 * d2 + (double)d3 * d3;
    }

    // ---- pw h1 ----
    if (tid < 128) {
        int r = 8 + (tid >> 4), l = tid & 15;
        const float* bp = xsf + r * XLD2;
        float pblk[4];
        #pragma unroll
        for (int kb = 0; kb < 4; ++kb) {
            float q[8];
            #pragma unroll
            for (int k = 0; k < 8; ++k) {
                float e = bp[kb * 128 + l + 16 * k];
                q[k] = __fmul_rn(e, e);
            }
            float V = __fadd_rn(__fadd_rn(__fadd_rn(q[0], q[1]), __fadd_rn(q[2], q[3])),
                                __fadd_rn(__fadd_rn(q[4], q[5]), __fadd_rn(q[6], q[7])));
            V = __fadd_rn(V, __shfl_xor(V, 8, 16));
            V = __fadd_rn(V, __shfl_xor(V, 4, 16));
            V = __fadd_rn(V, __shfl_xor(V, 2, 16));
            V = __fadd_rn(V, __shfl_xor(V, 1, 16));
            pblk[kb] = V;
        }
        if (l == 0)
            sxs[r] = __fadd_rn(__fadd_rn(pblk[0], pblk[1]), __fadd_rn(pblk[2], pblk[3]));
    }
    __syncthreads();                        // B5: sxs h1

    // ---- replay h1 (waves 2-3) ----
    {
        int np = pcnt[1] < PMH ? pcnt[1] : PMH;
        int pi = tid - 128;
        if (pi >= 0 && pi < np) {
            int r = prw[1][pi], c = pcd[1][pi];
            const float4* Ep4 = reinterpret_cast<const float4*>(E + (long)c * DD);
            const float4* Xp4 = reinterpret_cast<const float4*>(xsf + r * XLD2);
            float g = 0.f;
            #pragma unroll 4
            for (int jj = 0; jj < 128; ++jj) {
                float4 e4 = Ep4[jj], x4 = Xp4[jj];
                g = __fmaf_rn(x4.x, e4.x, g);
                g = __fmaf_rn(x4.y, e4.y, g);
                g = __fmaf_rn(x4.z, e4.z, g);
                g = __fmaf_rn(x4.w, e4.w, g);
            }
            float t1 = __fadd_rn(sxs[r], se[c]);
            float d  = __fsub_rn(t1, __fmul_rn(2.f, g));
            unsigned int bb = __float_as_uint(d);
            unsigned int u  = (bb & 0x80000000u) ? ~bb : (bb | 0x80000000u);
            atomicMin(&rmin[r], ((unsigned long long)u << 10) | (unsigned int)c);
        }
    }
    __syncthreads();                        // B6: rmin h1
    if (tid >= 8 && tid < 16 && fidx[tid] < 0 && !oflag[tid])
        fidx[tid] = (int)(rmin[tid] & 0x3ffu);

    // ---- overflow h1 (rare) ----
    if (oany & 2) {
        for (int r = 8; r < 16; ++r) {
            if (!oflag[r]) continue;
            const float4* Xp4 = reinterpret_cast<const float4*>(xsf + r * XLD2);
            float bd = 1e30f; int bi = KK;
            for (int q = 0; q < 4; ++q) {
                int c = q * BT2 + tid;
                const float4* Ep4 = reinterpret_cast<const float4*>(E + (long)c * DD);
                float g = 0.f;
                #pragma unroll 4
                for (int jj = 0; jj < 128; ++jj) {
                    float4 e4 = Ep4[jj], x4 = Xp4[jj];
                    g = __fmaf_rn(x4.x, e4.x, g);
                    g = __fmaf_rn(x4.y, e4.y, g);
                    g = __fmaf_rn(x4.z, e4.z, g);
                    g = __fmaf_rn(x4.w, e4.w, g);
                }
                float d = __fsub_rn(__fadd_rn(sxs[r], se[c]), __fmul_rn(2.f, g));
                if (d < bd) { bd = d; bi = c; }
            }
            #pragma unroll
            for (int off = 32; off; off >>= 1) {
                float tv = __shfl_down(bd, off, 64);
                int   ti = __shfl_down(bi, off, 64);
                if (tv < bd || (tv == bd && ti < bi)) { bd = tv; bi = ti; }
            }
            if (lane == 0) { owv[w] = bd; owi[w] = bi; }
            __syncthreads();
            if (tid == 0) {
                float BD = 1e30f; int BI = KK;
                #pragma unroll
                for (int ww = 0; ww < 4; ++ww)
                    if (owv[ww] < BD || (owv[ww] == BD && owi[ww] < BI)) { BD = owv[ww]; BI = owi[ww]; }
                fidx[r] = BI;
            }
            __syncthreads();
        }
    }
    __syncthreads();                        // B7: fidx h1 final

    if (tid < ROWS2)
        out[(size_t)NN * DD + 1 + nbase + tid] = (float)fidx[tid];

    // ---- gather h1 ----
    #pragma unroll
    for (int it = 0; it < 4; ++it) {
        int flat = it * BT2 + tid;
        int r = 8 + (flat >> 7);
        int j = (flat & 127) * 4;
        int idx = fidx[r];
        float4 ev = *reinterpret_cast<const float4*>(E + (long)idx * DD + j);
        float4 xv = *reinterpret_cast<const float4*>(&xsf[r * XLD2 + j]);
        float d0 = __fsub_rn(ev.x, xv.x);
        float d1 = __fsub_rn(ev.y, xv.y);
        float d2 = __fsub_rn(ev.z, xv.z);
        float d3 = __fsub_rn(ev.w, xv.w);
        float4 st;
        st.x = __fadd_rn(xv.x, d0); st.y = __fadd_rn(xv.y, d1);
        st.z = __fadd_rn(xv.z, d2); st.w = __fadd_rn(xv.w, d3);
        *reinterpret_cast<float4*>(out + (size_t)(nbase + r) * DD + j) = st;
        lacc += (double)d0 * d0 + (double)d1 * d1 + (double)d2 * d2 + (double)d3 * d3;
    }
    #pragma unroll
    for (int off = 32; off; off >>= 1) lacc += __shfl_down(lacc, off, 64);
    if (lane == 0) wloss[w] = lacc;
    __syncthreads();
    if (tid == 0)
        partials[blk] = wloss[0] + wloss[1] + wloss[2] + wloss[3];
}

// ---------------- loss finalize: sum 4096 block partials ----------------
__global__ void finalize_kernel(const double* __restrict__ partials, float* __restrict__ out) {
    __shared__ double sm[16];
    const int tid = threadIdx.x;                // 1024 threads
    const int w = tid >> 6, lane = tid & 63;
    double a = 0.0;
    #pragma unroll
    for (int i = 0; i < NBLK2 / 1024; ++i)
        a += partials[i * 1024 + tid];
    #pragma unroll
    for (int off = 32; off; off >>= 1) a += __shfl_down(a, off, 64);
    if (lane == 0) sm[w] = a;
    __syncthreads();
    if (tid == 0) {
        double s = 0.0;
        #pragma unroll
        for (int i = 0; i < 16; ++i) s += sm[i];
        out[(size_t)NN * DD] = (float)(1.25 * s / ((double)NN * DD));
    }
}

extern "C" void kernel_launch(void* const* d_in, const int* in_sizes, int n_in,
                              void* d_out, int out_size, void* d_ws, size_t ws_size,
                              hipStream_t stream) {
    const float* x = (const float*)d_in[0];
    const float* E = (const float*)d_in[1];
    float* out = (float*)d_out;
    double* partials = (double*)d_ws;                                       // 32 KB
    float* se = (float*)((char*)d_ws + 32768);                              // 4 KB
    unsigned short* Bph = (unsigned short*)((char*)d_ws + 65536);           // 1 MB
    unsigned long long* cands =
        (unsigned long long*)((char*)d_ws + 65536 + 1048576);               // 512 KB

    enorms_exact<<<4, 256, 0, stream>>>(E, se);
    pack_e<<<(KK * DD / 2) / 256, 256, 0, stream>>>(E, Bph);
    vq_filter<<<NN / ROWS, BLOCKT, 0, stream>>>(x, Bph, se, cands);
    vq_out<<<NBLK2, BT2, 0, stream>>>(x, E, se, cands, partials, out);
    finalize_kernel<<<1, 1024, 0, stream>>>(partials, out);
}

// Round 13
// 258.609 us; speedup vs baseline: 2.4815x; 1.0351x over previous
//
#include <hip/hip_runtime.h>

#define BB 16
#define DD 512
#define TT 4096
#define KK 1024
#define NN (BB*TT)              // 65536 rows
#define RWS 64                  // rows per block
#define BT 1024                 // 16 waves
#define NW 16
#define MARGIN 1e-3f            // candidate margin (req <=8e-4, 25% slack)
#define CM 6                    // candidate slots per row
#define PM 384                  // max replay pairs per block (64*6)
#define XLD 516                 // floats per x row (2064 B, 16B-aligned)
#define NPART (NN/RWS)          // 1024 partials

typedef __attribute__((ext_vector_type(8))) short short8v;   // 8 bf16
typedef __attribute__((ext_vector_type(4))) float f32x4;

// ---- bf16 helper (RNE) ----
__device__ __forceinline__ unsigned short f2bf(float f) {
    unsigned int u = __float_as_uint(f);
    unsigned int r = (u + 0x7fffu + ((u >> 16) & 1u)) >> 16;
    return (unsigned short)r;
}

// ---- numpy pairwise-sum replication (fp32, squares) — verified passing ----
__device__ __forceinline__ float pw128_sq_strided(const float* a, int stride) {
    float V[16];
    #pragma unroll
    for (int l = 0; l < 16; ++l) {
        float q[8];
        #pragma unroll
        for (int k = 0; k < 8; ++k) {
            float e = a[(l + 16 * k) * stride];
            q[k] = __fmul_rn(e, e);
        }
        V[l] = __fadd_rn(__fadd_rn(__fadd_rn(q[0], q[1]), __fadd_rn(q[2], q[3])),
                         __fadd_rn(__fadd_rn(q[4], q[5]), __fadd_rn(q[6], q[7])));
    }
    float u[8];
    #pragma unroll
    for (int l = 0; l < 8; ++l) u[l] = __fadd_rn(V[l], V[l + 8]);
    float v[4];
    #pragma unroll
    for (int l = 0; l < 4; ++l) v[l] = __fadd_rn(u[l], u[l + 4]);
    return __fadd_rn(__fadd_rn(v[0], v[2]), __fadd_rn(v[1], v[3]));
}
__device__ __forceinline__ float pw512_sq_strided(const float* a, int stride) {
    float p0 = pw128_sq_strided(a, stride);
    float p1 = pw128_sq_strided(a + 128 * stride, stride);
    float p2 = pw128_sq_strided(a + 256 * stride, stride);
    float p3 = pw128_sq_strided(a + 384 * stride, stride);
    return __fadd_rn(__fadd_rn(p0, p1), __fadd_rn(p2, p3));
}

// ---------------- exact ||e||^2 per code row ----------------
__global__ void enorms_exact(const float* __restrict__ E, float* __restrict__ se) {
    int i = blockIdx.x * blockDim.x + threadIdx.x;
    if (i < KK) se[i] = pw512_sq_strided(E + (long)i * DD, 1);
}

// ---------------- pack E (hi bf16) into MFMA B-fragment layout (u32 pairs) --
__global__ void pack_e(const float* __restrict__ E, unsigned short* __restrict__ Bph) {
    int i = blockIdx.x * blockDim.x + threadIdx.x;   // 0 .. KK*DD/2-1
    if (i >= KK * DD / 2) return;
    int c = i >> 8;
    int k = (i & 255) * 2;
    float2 v = *reinterpret_cast<const float2*>(E + ((long)c << 9) + k);
    int lane = (c & 15) + ((k >> 3) & 3) * 16;
    int hw = (((c >> 4) * 16 + (k >> 5)) * 64 + lane) * 8 + (k & 7);
    unsigned int pk = (unsigned int)f2bf(v.x) | ((unsigned int)f2bf(v.y) << 16);
    *reinterpret_cast<unsigned int*>(Bph + hw) = pk;
}

// ---- build bf16-hi A fragment from row-major f32 LDS row (r5-verified op) ----
__device__ __forceinline__ short8v build_frag_rm(const float* __restrict__ row, int c0) {
    union { short8v v; unsigned int wd[4]; } u;
    float4 a = *reinterpret_cast<const float4*>(row + c0);
    float4 b = *reinterpret_cast<const float4*>(row + c0 + 4);
    asm("v_cvt_pk_bf16_f32 %0, %1, %2" : "=v"(u.wd[0]) : "v"(a.x), "v"(a.y));
    asm("v_cvt_pk_bf16_f32 %0, %1, %2" : "=v"(u.wd[1]) : "v"(a.z), "v"(a.w));
    asm("v_cvt_pk_bf16_f32 %0, %1, %2" : "=v"(u.wd[2]) : "v"(b.x), "v"(b.y));
    asm("v_cvt_pk_bf16_f32 %0, %1, %2" : "=v"(u.wd[3]) : "v"(b.z), "v"(b.w));
    return u.v;
}

// =============== fused: filter + replay + argmin + gather/loss/st =========
__global__ __launch_bounds__(BT)
void vq_fused(const float* __restrict__ x, const float* __restrict__ E,
              const unsigned short* __restrict__ Bph,
              const float* __restrict__ se,
              double* __restrict__ partials, float* __restrict__ out) {
    __shared__ __align__(16) float xsf[RWS * XLD];   // 132,096 B row-major [r][d]
    __shared__ float wrowmin[NW * RWS];              // 4 KB
    __shared__ float gthr[RWS];
    __shared__ int   rcnt[RWS];
    __shared__ unsigned short rc[RWS][CM];
    __shared__ int   prow[PM];
    __shared__ int   pcand[PM];
    __shared__ unsigned long long rmin[RWS];
    __shared__ float sxs[RWS];
    __shared__ int   fidx[RWS];
    __shared__ int   oflag[RWS];
    __shared__ double wloss[NW];
    __shared__ int   pcnt, oany;

    const int tid  = threadIdx.x;
    const int w    = tid >> 6;
    const int lane = tid & 63;
    const int blk  = blockIdx.x;
    const int b    = blk >> 6;
    const int t0   = (blk & 63) * RWS;
    const long nbase = (long)b * TT + t0;
    const float* xb = x + (long)b * DD * TT + t0;

    if (tid < RWS) { rcnt[tid] = 0; rmin[tid] = ~0ull; oflag[tid] = 0; fidx[tid] = -1; }
    if (tid == 0) { pcnt = 0; oany = 0; }

    // ---- stage: float4 coalesced reads along t, row-major LDS [r][d] ----
    #pragma unroll
    for (int it = 0; it < 8; ++it) {
        int flat = it * BT + tid;               // 8192 float4
        int d  = flat >> 4;
        int r4 = (flat & 15) * 4;
        float4 v = *reinterpret_cast<const float4*>(xb + (long)d * TT + r4);
        xsf[(r4 + 0) * XLD + d] = v.x;
        xsf[(r4 + 1) * XLD + d] = v.y;
        xsf[(r4 + 2) * XLD + d] = v.z;
        xsf[(r4 + 3) * XLD + d] = v.w;
    }
    __syncthreads();                            // B1

    // ---- GEMM: wave owns 64 codes, K=512, A=hi(on-the-fly) x B=hi ----
    f32x4 acc[4][4];
    #pragma unroll
    for (int m = 0; m < 4; ++m)
        #pragma unroll
        for (int n = 0; n < 4; ++n)
            acc[m][n] = (f32x4){0.f, 0.f, 0.f, 0.f};

    const short8v* Bhv = (const short8v*)Bph;
    {
        const int rl  = lane & 15;
        const int lg8 = (lane >> 4) * 8;
        for (int kk = 0; kk < 16; ++kk) {
            short8v bh[4];
            #pragma unroll
            for (int n = 0; n < 4; ++n)
                bh[n] = Bhv[((w * 4 + n) * 16 + kk) * 64 + lane];
            short8v ah[4];
            #pragma unroll
            for (int m = 0; m < 4; ++m)
                ah[m] = build_frag_rm(xsf + (m * 16 + rl) * XLD, kk * 32 + lg8);
            #pragma unroll
            for (int n = 0; n < 4; ++n)
                #pragma unroll
                for (int m = 0; m < 4; ++m)
                    acc[m][n] = __builtin_amdgcn_mfma_f32_16x16x32_bf16(ah[m], bh[n], acc[m][n], 0, 0, 0);
        }
    }

    // ---- per-row wave-min (C/D: col=lane&15, row=(lane>>4)*4+reg) ----
    float sef[4];
    #pragma unroll
    for (int n = 0; n < 4; ++n) sef[n] = se[w * 64 + n * 16 + (lane & 15)];

    #pragma unroll
    for (int m = 0; m < 4; ++m) {
        #pragma unroll
        for (int r4 = 0; r4 < 4; ++r4) {
            float mn = 1e30f;
            #pragma unroll
            for (int n = 0; n < 4; ++n)
                mn = fminf(mn, fmaf(-2.f, acc[m][n][r4], sef[n]));
            #pragma unroll
            for (int off = 1; off < 16; off <<= 1)
                mn = fminf(mn, __shfl_xor(mn, off, 64));
            if ((lane & 15) == 0)
                wrowmin[w * RWS + m * 16 + (lane >> 4) * 4 + r4] = mn;
        }
    }
    __syncthreads();                            // B2

    if (tid < RWS) {
        float g = 1e30f;
        #pragma unroll
        for (int ww = 0; ww < NW; ++ww)
            g = fminf(g, wrowmin[ww * RWS + tid]);
        gthr[tid] = g + MARGIN;
    }
    __syncthreads();                            // B3

    // ---- push candidates (acc-based) || pw for ||x||^2 (all 1024 threads) ----
    #pragma unroll
    for (int m = 0; m < 4; ++m) {
        #pragma unroll
        for (int r4 = 0; r4 < 4; ++r4) {
            int row = m * 16 + (lane >> 4) * 4 + r4;
            float th = gthr[row];
            #pragma unroll
            for (int n = 0; n < 4; ++n) {
                float sc = fmaf(-2.f, acc[m][n][r4], sef[n]);
                if (sc <= th) {
                    int pos = atomicAdd(&rcnt[row], 1);
                    if (pos < CM)
                        rc[row][pos] = (unsigned short)(w * 64 + n * 16 + (lane & 15));
                }
            }
        }
    }
    {   // pw: r = tid>>4 (all 64 rows), 16-lane butterfly (r12-verified numerics)
        int r = tid >> 4, l = tid & 15;
        const float* bp = xsf + r * XLD;
        float pblk[4];
        #pragma unroll
        for (int kb = 0; kb < 4; ++kb) {
            float q[8];
            #pragma unroll
            for (int k = 0; k < 8; ++k) {
                float e = bp[kb * 128 + l + 16 * k];
                q[k] = __fmul_rn(e, e);
            }
            float V = __fadd_rn(__fadd_rn(__fadd_rn(q[0], q[1]), __fadd_rn(q[2], q[3])),
                                __fadd_rn(__fadd_rn(q[4], q[5]), __fadd_rn(q[6], q[7])));
            V = __fadd_rn(V, __shfl_xor(V, 8, 16));
            V = __fadd_rn(V, __shfl_xor(V, 4, 16));
            V = __fadd_rn(V, __shfl_xor(V, 2, 16));
            V = __fadd_rn(V, __shfl_xor(V, 1, 16));
            pblk[kb] = V;
        }
        if (l == 0)
            sxs[r] = __fadd_rn(__fadd_rn(pblk[0], pblk[1]), __fadd_rn(pblk[2], pblk[3]));
    }
    __syncthreads();                            // B4

    // ---- pair list build + single-cand fast path (tid<64) ----
    if (tid < RWS) {
        int cnt = rcnt[tid];
        if (cnt == 1) {
            fidx[tid] = (int)rc[tid][0];
        } else if (cnt <= CM) {
            int base = atomicAdd(&pcnt, cnt);
            for (int i = 0; i < cnt; ++i) {
                prow[base + i]  = tid;
                pcand[base + i] = (int)rc[tid][i];
            }
        } else {
            oflag[tid] = 1;
            atomicOr(&oany, 1);
        }
    }
    __syncthreads();                            // B5

    // ---- exact fp32 replay (numpy semantics), spread over 16 waves ----
    const int np = (pcnt < PM) ? pcnt : PM;
    {
        int p = lane * NW + w;
        if (p < np) {
            int r = prow[p], c = pcand[p];
            const float4* Ep4 = reinterpret_cast<const float4*>(E + (long)c * DD);
            const float4* Xp4 = reinterpret_cast<const float4*>(xsf + r * XLD);
            float g = 0.f;
            #pragma unroll 4
            for (int jj = 0; jj < 128; ++jj) {
                float4 e4 = Ep4[jj], x4 = Xp4[jj];
                g = __fmaf_rn(x4.x, e4.x, g);   // exact numpy order
                g = __fmaf_rn(x4.y, e4.y, g);
                g = __fmaf_rn(x4.z, e4.z, g);
                g = __fmaf_rn(x4.w, e4.w, g);
            }
            float t1 = __fadd_rn(sxs[r], se[c]);
            float d  = __fsub_rn(t1, __fmul_rn(2.f, g));
            unsigned int bb = __float_as_uint(d);
            unsigned int u  = (bb & 0x80000000u) ? ~bb : (bb | 0x80000000u);
            atomicMin(&rmin[r], ((unsigned long long)u << 10) | (unsigned int)c);
        }
    }
    __syncthreads();                            // B6

    if (tid < RWS && fidx[tid] < 0 && !oflag[tid])
        fidx[tid] = (int)(rmin[tid] & 0x3ffu);

    // ---- overflow fallback (rare): 1 code/thread full replay ----
    if (oany) {
        for (int r = 0; r < RWS; ++r) {
            if (!oflag[r]) continue;            // LDS-uniform branch
            const float4* Xp4 = reinterpret_cast<const float4*>(xsf + r * XLD);
            int c = tid;                        // KK == BT
            const float4* Ep4 = reinterpret_cast<const float4*>(E + (long)c * DD);
            float g = 0.f;
            #pragma unroll 4
            for (int jj = 0; jj < 128; ++jj) {
                float4 e4 = Ep4[jj], x4 = Xp4[jj];
                g = __fmaf_rn(x4.x, e4.x, g);
                g = __fmaf_rn(x4.y, e4.y, g);
                g = __fmaf_rn(x4.z, e4.z, g);
                g = __fmaf_rn(x4.w, e4.w, g);
            }
            float bd = __fsub_rn(__fadd_rn(sxs[r], se[c]), __fmul_rn(2.f, g));
            int bi = c;
            #pragma unroll
            for (int off = 32; off; off >>= 1) {
                float tv = __shfl_down(bd, off, 64);
                int   ti = __shfl_down(bi, off, 64);
                if (tv < bd || (tv == bd && ti < bi)) { bd = tv; bi = ti; }
            }
            if (lane == 0) {
                unsigned int bb = __float_as_uint(bd);
                unsigned int u  = (bb & 0x80000000u) ? ~bb : (bb | 0x80000000u);
                atomicMin(&rmin[r], ((unsigned long long)u << 10) | (unsigned int)bi);
            }
            __syncthreads();
            if (tid == 0) fidx[r] = (int)(rmin[r] & 0x3ffu);
        }
    }
    __syncthreads();                            // B7: fidx final

    if (tid < RWS)
        out[(size_t)NN * DD + 1 + nbase + tid] = (float)fidx[tid];

    // ---- gather rows, quantized_st = fl(x + fl(q-x)), fp64 loss ----
    double lacc = 0.0;
    #pragma unroll
    for (int it = 0; it < 8; ++it) {
        int flat = it * BT + tid;               // 8192 float4 = 64 rows * 128
        int r = flat >> 7;
        int j = (flat & 127) * 4;
        int idx = fidx[r];
        float4 ev = *reinterpret_cast<const float4*>(E + (long)idx * DD + j);
        float4 xv = *reinterpret_cast<const float4*>(&xsf[r * XLD + j]);
        float d0 = __fsub_rn(ev.x, xv.x);
        float d1 = __fsub_rn(ev.y, xv.y);
        float d2 = __fsub_rn(ev.z, xv.z);
        float d3 = __fsub_rn(ev.w, xv.w);
        float4 st;
        st.x = __fadd_rn(xv.x, d0); st.y = __fadd_rn(xv.y, d1);
        st.z = __fadd_rn(xv.z, d2); st.w = __fadd_rn(xv.w, d3);
        *reinterpret_cast<float4*>(out + (size_t)(nbase + r) * DD + j) = st;
        lacc += (double)d0 * d0 + (double)d1 * d1 + (double)d2 * d2 + (double)d3 * d3;
    }
    #pragma unroll
    for (int off = 32; off; off >>= 1) lacc += __shfl_down(lacc, off, 64);
    if (lane == 0) wloss[w] = lacc;
    __syncthreads();
    if (tid == 0) {
        double s = 0.0;
        #pragma unroll
        for (int ww = 0; ww < NW; ++ww) s += wloss[ww];
        partials[blk] = s;                      // plain store, no atomic
    }
}

// ---------------- loss finalize: sum 1024 block partials ----------------
__global__ void finalize_kernel(const double* __restrict__ partials, float* __restrict__ out) {
    __shared__ double sm[16];
    const int tid = threadIdx.x;                // 1024 threads
    const int w = tid >> 6, lane = tid & 63;
    double a = partials[tid];
    #pragma unroll
    for (int off = 32; off; off >>= 1) a += __shfl_down(a, off, 64);
    if (lane == 0) sm[w] = a;
    __syncthreads();
    if (tid == 0) {
        double s = 0.0;
        #pragma unroll
        for (int i = 0; i < 16; ++i) s += sm[i];
        out[(size_t)NN * DD] = (float)(1.25 * s / ((double)NN * DD));
    }
}

extern "C" void kernel_launch(void* const* d_in, const int* in_sizes, int n_in,
                              void* d_out, int out_size, void* d_ws, size_t ws_size,
                              hipStream_t stream) {
    const float* x = (const float*)d_in[0];
    const float* E = (const float*)d_in[1];
    float* out = (float*)d_out;
    double* partials = (double*)d_ws;                                   // 8 KB
    float* se = (float*)((char*)d_ws + 32768);                          // 4 KB
    unsigned short* Bph = (unsigned short*)((char*)d_ws + 65536);       // 1 MB

    enorms_exact<<<4, 256, 0, stream>>>(E, se);
    pack_e<<<(KK * DD / 2) / 256, 256, 0, stream>>>(E, Bph);
    vq_fused<<<NPART, BT, 0, stream>>>(x, E, Bph, se, partials, out);
    finalize_kernel<<<1, 1024, 0, stream>>>(partials, out);
}

// Round 14
// 224.533 us; speedup vs baseline: 2.8581x; 1.1518x over previous
//
#include <hip/hip_runtime.h>

#define BB 16
#define DD 512
#define TT 4096
#define KK 1024
#define NN (BB*TT)              // 65536 rows
#define RWS 32                  // rows per block
#define BT 512                  // 8 waves
#define NW 8
#define MARGIN 1e-3f            // candidate margin (req <=8e-4, 25% slack)
#define CM 6                    // candidate slots per row
#define PM 192                  // max replay pairs per block (32*6)
#define XLD 516                 // floats per x row (2064 B, 16B-aligned)
#define NPART (NN/RWS)          // 2048 partials

typedef __attribute__((ext_vector_type(8))) short short8v;   // 8 bf16
typedef __attribute__((ext_vector_type(4))) float f32x4;

// ---- bf16 helper (RNE) ----
__device__ __forceinline__ unsigned short f2bf(float f) {
    unsigned int u = __float_as_uint(f);
    unsigned int r = (u + 0x7fffu + ((u >> 16) & 1u)) >> 16;
    return (unsigned short)r;
}

// ---- numpy pairwise-sum replication (fp32, squares) — verified passing ----
__device__ __forceinline__ float pw128_sq_strided(const float* a, int stride) {
    float V[16];
    #pragma unroll
    for (int l = 0; l < 16; ++l) {
        float q[8];
        #pragma unroll
        for (int k = 0; k < 8; ++k) {
            float e = a[(l + 16 * k) * stride];
            q[k] = __fmul_rn(e, e);
        }
        V[l] = __fadd_rn(__fadd_rn(__fadd_rn(q[0], q[1]), __fadd_rn(q[2], q[3])),
                         __fadd_rn(__fadd_rn(q[4], q[5]), __fadd_rn(q[6], q[7])));
    }
    float u[8];
    #pragma unroll
    for (int l = 0; l < 8; ++l) u[l] = __fadd_rn(V[l], V[l + 8]);
    float v[4];
    #pragma unroll
    for (int l = 0; l < 4; ++l) v[l] = __fadd_rn(u[l], u[l + 4]);
    return __fadd_rn(__fadd_rn(v[0], v[2]), __fadd_rn(v[1], v[3]));
}
__device__ __forceinline__ float pw512_sq_strided(const float* a, int stride) {
    float p0 = pw128_sq_strided(a, stride);
    float p1 = pw128_sq_strided(a + 128 * stride, stride);
    float p2 = pw128_sq_strided(a + 256 * stride, stride);
    float p3 = pw128_sq_strided(a + 384 * stride, stride);
    return __fadd_rn(__fadd_rn(p0, p1), __fadd_rn(p2, p3));
}

// ---------------- exact ||e||^2 per code row ----------------
__global__ void enorms_exact(const float* __restrict__ E, float* __restrict__ se) {
    int i = blockIdx.x * blockDim.x + threadIdx.x;
    if (i < KK) se[i] = pw512_sq_strided(E + (long)i * DD, 1);
}

// ---------------- pack E (hi bf16) into MFMA B-fragment layout (u32 pairs) --
__global__ void pack_e(const float* __restrict__ E, unsigned short* __restrict__ Bph) {
    int i = blockIdx.x * blockDim.x + threadIdx.x;   // 0 .. KK*DD/2-1
    if (i >= KK * DD / 2) return;
    int c = i >> 8;
    int k = (i & 255) * 2;
    float2 v = *reinterpret_cast<const float2*>(E + ((long)c << 9) + k);
    int lane = (c & 15) + ((k >> 3) & 3) * 16;
    int hw = (((c >> 4) * 16 + (k >> 5)) * 64 + lane) * 8 + (k & 7);
    unsigned int pk = (unsigned int)f2bf(v.x) | ((unsigned int)f2bf(v.y) << 16);
    *reinterpret_cast<unsigned int*>(Bph + hw) = pk;
}

// ---- build bf16-hi A fragment from row-major f32 LDS row (r5/r13-verified) ----
__device__ __forceinline__ short8v build_frag_rm(const float* __restrict__ row, int c0) {
    union { short8v v; unsigned int wd[4]; } u;
    float4 a = *reinterpret_cast<const float4*>(row + c0);
    float4 b = *reinterpret_cast<const float4*>(row + c0 + 4);
    asm("v_cvt_pk_bf16_f32 %0, %1, %2" : "=v"(u.wd[0]) : "v"(a.x), "v"(a.y));
    asm("v_cvt_pk_bf16_f32 %0, %1, %2" : "=v"(u.wd[1]) : "v"(a.z), "v"(a.w));
    asm("v_cvt_pk_bf16_f32 %0, %1, %2" : "=v"(u.wd[2]) : "v"(b.x), "v"(b.y));
    asm("v_cvt_pk_bf16_f32 %0, %1, %2" : "=v"(u.wd[3]) : "v"(b.z), "v"(b.w));
    return u.v;
}

// =============== fused (2 blocks/CU): filter + replay + gather/loss/st ====
__global__ __launch_bounds__(BT)
void vq_fused(const float* __restrict__ x, const float* __restrict__ E,
              const unsigned short* __restrict__ Bph,
              const float* __restrict__ se,
              double* __restrict__ partials, float* __restrict__ out) {
    __shared__ __align__(16) float xsf[RWS * XLD];   // 66,048 B row-major [r][d]
    __shared__ float wrowmin[NW * RWS];              // 1 KB
    __shared__ float gthr[RWS];
    __shared__ int   rcnt[RWS];
    __shared__ unsigned short rc[RWS][CM];
    __shared__ int   prow[PM];
    __shared__ int   pcand[PM];
    __shared__ unsigned long long rmin[RWS];
    __shared__ float sxs[RWS];
    __shared__ int   fidx[RWS];
    __shared__ int   oflag[RWS];
    __shared__ double wloss[NW];
    __shared__ int   pcnt, oany;

    const int tid  = threadIdx.x;
    const int w    = tid >> 6;              // 0..7
    const int lane = tid & 63;
    const int blk  = blockIdx.x;
    const int b    = blk >> 7;              // 128 blocks per batch
    const int t0   = (blk & 127) * RWS;
    const long nbase = (long)b * TT + t0;
    const float* xb = x + (long)b * DD * TT + t0;

    if (tid < RWS) { rcnt[tid] = 0; rmin[tid] = ~0ull; oflag[tid] = 0; fidx[tid] = -1; }
    if (tid == 0) { pcnt = 0; oany = 0; }

    // ---- stage: dword loads (lane&31 = row t), float4 LDS writes (2-way) ----
    {
        const int r  = lane & 31;
        const int dh = lane >> 5;           // 0/1
        const float* xbl = xb + r;
        #pragma unroll
        for (int it = 0; it < 4; ++it) {
            int d0 = ((it * NW + w) * 2 + dh) * 8;      // 0..504, step 8
            float v[8];
            #pragma unroll
            for (int jj = 0; jj < 8; ++jj)
                v[jj] = xbl[(long)(d0 + jj) * TT];
            float4 lo = {v[0], v[1], v[2], v[3]};
            float4 hi = {v[4], v[5], v[6], v[7]};
            *reinterpret_cast<float4*>(&xsf[r * XLD + d0])     = lo;  // bank step 4/row -> 2-way
            *reinterpret_cast<float4*>(&xsf[r * XLD + d0 + 4]) = hi;
        }
    }
    __syncthreads();                            // B1

    // ---- GEMM: wave owns 128 codes (8 n-tiles), 2 m-tiles, K=512 ----
    f32x4 acc[2][8];
    #pragma unroll
    for (int m = 0; m < 2; ++m)
        #pragma unroll
        for (int n = 0; n < 8; ++n)
            acc[m][n] = (f32x4){0.f, 0.f, 0.f, 0.f};

    const short8v* Bhv = (const short8v*)Bph;
    {
        const int rl  = lane & 15;
        const int lg8 = (lane >> 4) * 8;
        for (int kk = 0; kk < 16; ++kk) {
            short8v ah[2];
            #pragma unroll
            for (int m = 0; m < 2; ++m)
                ah[m] = build_frag_rm(xsf + (m * 16 + rl) * XLD, kk * 32 + lg8);
            #pragma unroll
            for (int nh = 0; nh < 2; ++nh) {    // 4 B-fragments at a time (reg pressure)
                short8v bh[4];
                #pragma unroll
                for (int q = 0; q < 4; ++q)
                    bh[q] = Bhv[((w * 8 + nh * 4 + q) * 16 + kk) * 64 + lane];
                #pragma unroll
                for (int q = 0; q < 4; ++q)
                    #pragma unroll
                    for (int m = 0; m < 2; ++m)
                        acc[m][nh * 4 + q] = __builtin_amdgcn_mfma_f32_16x16x32_bf16(
                            ah[m], bh[q], acc[m][nh * 4 + q], 0, 0, 0);
            }
        }
    }

    // ---- per-row wave-min (C/D: col=lane&15, row=(lane>>4)*4+reg) ----
    float sef[8];
    #pragma unroll
    for (int n = 0; n < 8; ++n) sef[n] = se[w * 128 + n * 16 + (lane & 15)];

    #pragma unroll
    for (int m = 0; m < 2; ++m) {
        #pragma unroll
        for (int r4 = 0; r4 < 4; ++r4) {
            float mn = 1e30f;
            #pragma unroll
            for (int n = 0; n < 8; ++n)
                mn = fminf(mn, fmaf(-2.f, acc[m][n][r4], sef[n]));
            #pragma unroll
            for (int off = 1; off < 16; off <<= 1)
                mn = fminf(mn, __shfl_xor(mn, off, 64));
            if ((lane & 15) == 0)
                wrowmin[w * RWS + m * 16 + (lane >> 4) * 4 + r4] = mn;
        }
    }
    __syncthreads();                            // B2

    if (tid < RWS) {
        float g = 1e30f;
        #pragma unroll
        for (int ww = 0; ww < NW; ++ww)
            g = fminf(g, wrowmin[ww * RWS + tid]);
        gthr[tid] = g + MARGIN;
    }
    __syncthreads();                            // B3

    // ---- push candidates (acc-based) || pw for ||x||^2 (all 512 threads) ----
    #pragma unroll
    for (int m = 0; m < 2; ++m) {
        #pragma unroll
        for (int r4 = 0; r4 < 4; ++r4) {
            int row = m * 16 + (lane >> 4) * 4 + r4;
            float th = gthr[row];
            #pragma unroll
            for (int n = 0; n < 8; ++n) {
                float sc = fmaf(-2.f, acc[m][n][r4], sef[n]);
                if (sc <= th) {
                    int pos = atomicAdd(&rcnt[row], 1);
                    if (pos < CM)
                        rc[row][pos] = (unsigned short)(w * 128 + n * 16 + (lane & 15));
                }
            }
        }
    }
    {   // pw: r = tid>>4 (32 rows x 16 threads), r12-verified numerics
        int r = tid >> 4, l = tid & 15;
        const float* bp = xsf + r * XLD;
        float pblk[4];
        #pragma unroll
        for (int kb = 0; kb < 4; ++kb) {
            float q[8];
            #pragma unroll
            for (int k = 0; k < 8; ++k) {
                float e = bp[kb * 128 + l + 16 * k];
                q[k] = __fmul_rn(e, e);
            }
            float V = __fadd_rn(__fadd_rn(__fadd_rn(q[0], q[1]), __fadd_rn(q[2], q[3])),
                                __fadd_rn(__fadd_rn(q[4], q[5]), __fadd_rn(q[6], q[7])));
            V = __fadd_rn(V, __shfl_xor(V, 8, 16));
            V = __fadd_rn(V, __shfl_xor(V, 4, 16));
            V = __fadd_rn(V, __shfl_xor(V, 2, 16));
            V = __fadd_rn(V, __shfl_xor(V, 1, 16));
            pblk[kb] = V;
        }
        if (l == 0)
            sxs[r] = __fadd_rn(__fadd_rn(pblk[0], pblk[1]), __fadd_rn(pblk[2], pblk[3]));
    }
    __syncthreads();                            // B4

    // ---- pair list build + single-cand fast path (tid<32) ----
    if (tid < RWS) {
        int cnt = rcnt[tid];
        if (cnt == 1) {
            fidx[tid] = (int)rc[tid][0];
        } else if (cnt <= CM) {
            int base = atomicAdd(&pcnt, cnt);
            for (int i = 0; i < cnt; ++i) {
                prow[base + i]  = tid;
                pcand[base + i] = (int)rc[tid][i];
            }
        } else {
            oflag[tid] = 1;
            atomicOr(&oany, 1);
        }
    }
    __syncthreads();                            // B5

    // ---- exact fp32 replay (numpy semantics), spread over 8 waves ----
    const int np = (pcnt < PM) ? pcnt : PM;
    {
        int p = lane * NW + w;
        if (p < np) {
            int r = prow[p], c = pcand[p];
            const float4* Ep4 = reinterpret_cast<const float4*>(E + (long)c * DD);
            const float4* Xp4 = reinterpret_cast<const float4*>(xsf + r * XLD);
            float g = 0.f;
            #pragma unroll 4
            for (int jj = 0; jj < 128; ++jj) {
                float4 e4 = Ep4[jj], x4 = Xp4[jj];
                g = __fmaf_rn(x4.x, e4.x, g);   // exact numpy order
                g = __fmaf_rn(x4.y, e4.y, g);
                g = __fmaf_rn(x4.z, e4.z, g);
                g = __fmaf_rn(x4.w, e4.w, g);
            }
            float t1 = __fadd_rn(sxs[r], se[c]);
            float d  = __fsub_rn(t1, __fmul_rn(2.f, g));
            unsigned int bb = __float_as_uint(d);
            unsigned int u  = (bb & 0x80000000u) ? ~bb : (bb | 0x80000000u);
            atomicMin(&rmin[r], ((unsigned long long)u << 10) | (unsigned int)c);
        }
    }
    __syncthreads();                            // B6

    if (tid < RWS && fidx[tid] < 0 && !oflag[tid])
        fidx[tid] = (int)(rmin[tid] & 0x3ffu);

    // ---- overflow fallback (rare): 2 codes/thread full replay ----
    if (oany) {
        for (int r = 0; r < RWS; ++r) {
            if (!oflag[r]) continue;            // LDS-uniform branch
            const float4* Xp4 = reinterpret_cast<const float4*>(xsf + r * XLD);
            float bd = 1e30f; int bi = KK;
            #pragma unroll
            for (int q = 0; q < 2; ++q) {
                int c = q * BT + tid;           // ascending c => strict < keeps lowest
                const float4* Ep4 = reinterpret_cast<const float4*>(E + (long)c * DD);
                float g = 0.f;
                #pragma unroll 4
                for (int jj = 0; jj < 128; ++jj) {
                    float4 e4 = Ep4[jj], x4 = Xp4[jj];
                    g = __fmaf_rn(x4.x, e4.x, g);
                    g = __fmaf_rn(x4.y, e4.y, g);
                    g = __fmaf_rn(x4.z, e4.z, g);
                    g = __fmaf_rn(x4.w, e4.w, g);
                }
                float d = __fsub_rn(__fadd_rn(sxs[r], se[c]), __fmul_rn(2.f, g));
                if (d < bd) { bd = d; bi = c; }
            }
            #pragma unroll
            for (int off = 32; off; off >>= 1) {
                float tv = __shfl_down(bd, off, 64);
                int   ti = __shfl_down(bi, off, 64);
                if (tv < bd || (tv == bd && ti < bi)) { bd = tv; bi = ti; }
            }
            if (lane == 0) {
                unsigned int bb = __float_as_uint(bd);
                unsigned int u  = (bb & 0x80000000u) ? ~bb : (bb | 0x80000000u);
                atomicMin(&rmin[r], ((unsigned long long)u << 10) | (unsigned int)bi);
            }
            __syncthreads();
            if (tid == 0) fidx[r] = (int)(rmin[r] & 0x3ffu);
        }
    }
    __syncthreads();                            // B7: fidx final

    if (tid < RWS)
        out[(size_t)NN * DD + 1 + nbase + tid] = (float)fidx[tid];

    // ---- gather rows, quantized_st = fl(x + fl(q-x)), fp64 loss ----
    double lacc = 0.0;
    #pragma unroll
    for (int it = 0; it < 8; ++it) {
        int flat = it * BT + tid;               // 4096 float4 = 32 rows * 128
        int r = flat >> 7;
        int j = (flat & 127) * 4;
        int idx = fidx[r];
        float4 ev = *reinterpret_cast<const float4*>(E + (long)idx * DD + j);
        float4 xv = *reinterpret_cast<const float4*>(&xsf[r * XLD + j]);
        float d0 = __fsub_rn(ev.x, xv.x);
        float d1 = __fsub_rn(ev.y, xv.y);
        float d2 = __fsub_rn(ev.z, xv.z);
        float d3 = __fsub_rn(ev.w, xv.w);
        float4 st;
        st.x = __fadd_rn(xv.x, d0); st.y = __fadd_rn(xv.y, d1);
        st.z = __fadd_rn(xv.z, d2); st.w = __fadd_rn(xv.w, d3);
        *reinterpret_cast<float4*>(out + (size_t)(nbase + r) * DD + j) = st;
        lacc += (double)d0 * d0 + (double)d1 * d1 + (double)d2 * d2 + (double)d3 * d3;
    }
    #pragma unroll
    for (int off = 32; off; off >>= 1) lacc += __shfl_down(lacc, off, 64);
    if (lane == 0) wloss[w] = lacc;
    __syncthreads();
    if (tid == 0) {
        double s = 0.0;
        #pragma unroll
        for (int ww = 0; ww < NW; ++ww) s += wloss[ww];
        partials[blk] = s;                      // plain store, no atomic
    }
}

// ---------------- loss finalize: sum 2048 block partials ----------------
__global__ void finalize_kernel(const double* __restrict__ partials, float* __restrict__ out) {
    __shared__ double sm[16];
    const int tid = threadIdx.x;                // 1024 threads
    const int w = tid >> 6, lane = tid & 63;
    double a = partials[tid] + partials[tid + 1024];
    #pragma unroll
    for (int off = 32; off; off >>= 1) a += __shfl_down(a, off, 64);
    if (lane == 0) sm[w] = a;
    __syncthreads();
    if (tid == 0) {
        double s = 0.0;
        #pragma unroll
        for (int i = 0; i < 16; ++i) s += sm[i];
        out[(size_t)NN * DD] = (float)(1.25 * s / ((double)NN * DD));
    }
}

extern "C" void kernel_launch(void* const* d_in, const int* in_sizes, int n_in,
                              void* d_out, int out_size, void* d_ws, size_t ws_size,
                              hipStream_t stream) {
    const float* x = (const float*)d_in[0];
    const float* E = (const float*)d_in[1];
    float* out = (float*)d_out;
    double* partials = (double*)d_ws;                                   // 16 KB
    float* se = (float*)((char*)d_ws + 32768);                          // 4 KB
    unsigned short* Bph = (unsigned short*)((char*)d_ws + 65536);       // 1 MB

    enorms_exact<<<4, 256, 0, stream>>>(E, se);
    pack_e<<<(KK * DD / 2) / 256, 256, 0, stream>>>(E, Bph);
    vq_fused<<<NPART, BT, 0, stream>>>(x, E, Bph, se, partials, out);
    finalize_kernel<<<1, 1024, 0, stream>>>(partials, out);
}

// Round 15
// 211.844 us; speedup vs baseline: 3.0293x; 1.0599x over previous
//
#include <hip/hip_runtime.h>

#define BB 16
#define DD 512
#define TT 4096
#define KK 1024
#define NN (BB*TT)              // 65536 rows
#define RWS 32                  // rows per block
#define BT 512                  // 8 waves
#define NW 8
#define MARGIN 1e-3f            // candidate margin (req <=8e-4, 25% slack)
#define CM 6                    // candidate slots per row
#define XLD 516                 // floats per x row (2064 B, 16B-aligned)
#define NPART (NN/RWS)          // 2048 partials

typedef __attribute__((ext_vector_type(8))) short short8v;   // 8 bf16
typedef __attribute__((ext_vector_type(4))) float f32x4;

// ---- bf16 helper (RNE) ----
__device__ __forceinline__ unsigned short f2bf(float f) {
    unsigned int u = __float_as_uint(f);
    unsigned int r = (u + 0x7fffu + ((u >> 16) & 1u)) >> 16;
    return (unsigned short)r;
}

// ---- sortable-float mapping (monotone: f1<f2 <=> u1<u2) ----
__device__ __forceinline__ unsigned int f2sort(float f) {
    unsigned int b = __float_as_uint(f);
    return (b & 0x80000000u) ? ~b : (b | 0x80000000u);
}
__device__ __forceinline__ float sort2f(unsigned int u) {
    unsigned int b = (u & 0x80000000u) ? (u & 0x7fffffffu) : ~u;
    return __uint_as_float(b);
}

// ---- numpy pairwise-sum replication (fp32, squares) — verified passing ----
__device__ __forceinline__ float pw128_sq_strided(const float* a, int stride) {
    float V[16];
    #pragma unroll
    for (int l = 0; l < 16; ++l) {
        float q[8];
        #pragma unroll
        for (int k = 0; k < 8; ++k) {
            float e = a[(l + 16 * k) * stride];
            q[k] = __fmul_rn(e, e);
        }
        V[l] = __fadd_rn(__fadd_rn(__fadd_rn(q[0], q[1]), __fadd_rn(q[2], q[3])),
                         __fadd_rn(__fadd_rn(q[4], q[5]), __fadd_rn(q[6], q[7])));
    }
    float u[8];
    #pragma unroll
    for (int l = 0; l < 8; ++l) u[l] = __fadd_rn(V[l], V[l + 8]);
    float v[4];
    #pragma unroll
    for (int l = 0; l < 4; ++l) v[l] = __fadd_rn(u[l], u[l + 4]);
    return __fadd_rn(__fadd_rn(v[0], v[2]), __fadd_rn(v[1], v[3]));
}
__device__ __forceinline__ float pw512_sq_strided(const float* a, int stride) {
    float p0 = pw128_sq_strided(a, stride);
    float p1 = pw128_sq_strided(a + 128 * stride, stride);
    float p2 = pw128_sq_strided(a + 256 * stride, stride);
    float p3 = pw128_sq_strided(a + 384 * stride, stride);
    return __fadd_rn(__fadd_rn(p0, p1), __fadd_rn(p2, p3));
}

// ---------------- exact ||e||^2 per code row ----------------
__global__ void enorms_exact(const float* __restrict__ E, float* __restrict__ se) {
    int i = blockIdx.x * blockDim.x + threadIdx.x;
    if (i < KK) se[i] = pw512_sq_strided(E + (long)i * DD, 1);
}

// ---------------- pack E (hi bf16) into MFMA B-fragment layout (u32 pairs) --
__global__ void pack_e(const float* __restrict__ E, unsigned short* __restrict__ Bph) {
    int i = blockIdx.x * blockDim.x + threadIdx.x;   // 0 .. KK*DD/2-1
    if (i >= KK * DD / 2) return;
    int c = i >> 8;
    int k = (i & 255) * 2;
    float2 v = *reinterpret_cast<const float2*>(E + ((long)c << 9) + k);
    int lane = (c & 15) + ((k >> 3) & 3) * 16;
    int hw = (((c >> 4) * 16 + (k >> 5)) * 64 + lane) * 8 + (k & 7);
    unsigned int pk = (unsigned int)f2bf(v.x) | ((unsigned int)f2bf(v.y) << 16);
    *reinterpret_cast<unsigned int*>(Bph + hw) = pk;
}

// ---- build bf16-hi A fragment from row-major f32 LDS row (r5/r13-verified) ----
__device__ __forceinline__ short8v build_frag_rm(const float* __restrict__ row, int c0) {
    union { short8v v; unsigned int wd[4]; } u;
    float4 a = *reinterpret_cast<const float4*>(row + c0);
    float4 b = *reinterpret_cast<const float4*>(row + c0 + 4);
    asm("v_cvt_pk_bf16_f32 %0, %1, %2" : "=v"(u.wd[0]) : "v"(a.x), "v"(a.y));
    asm("v_cvt_pk_bf16_f32 %0, %1, %2" : "=v"(u.wd[1]) : "v"(a.z), "v"(a.w));
    asm("v_cvt_pk_bf16_f32 %0, %1, %2" : "=v"(u.wd[2]) : "v"(b.x), "v"(b.y));
    asm("v_cvt_pk_bf16_f32 %0, %1, %2" : "=v"(u.wd[3]) : "v"(b.z), "v"(b.w));
    return u.v;
}

// =============== fused (2 blocks/CU, 6 barriers) ===============
__global__ __launch_bounds__(BT)
void vq_fused(const float* __restrict__ x, const float* __restrict__ E,
              const unsigned short* __restrict__ Bph,
              const float* __restrict__ se,
              double* __restrict__ partials, float* __restrict__ out) {
    __shared__ __align__(16) float xsf[RWS * XLD];   // 66,048 B row-major [r][d]
    __shared__ unsigned int rowmin[RWS];             // sortable-bits global row min
    __shared__ int   rcnt[RWS];
    __shared__ unsigned short rc[RWS][CM];
    __shared__ unsigned long long rmin[RWS];
    __shared__ float sxs[RWS];
    __shared__ int   fidx[RWS];
    __shared__ int   oflag[RWS];
    __shared__ double wloss[NW];
    __shared__ int   oany;

    const int tid  = threadIdx.x;
    const int w    = tid >> 6;              // 0..7
    const int lane = tid & 63;
    const int blk  = blockIdx.x;
    const int b    = blk >> 7;              // 128 blocks per batch
    const int t0   = (blk & 127) * RWS;
    const long nbase = (long)b * TT + t0;
    const float* xb = x + (long)b * DD * TT + t0;

    if (tid < RWS) {
        rcnt[tid] = 0; rowmin[tid] = 0xFFFFFFFFu; rmin[tid] = ~0ull;
        oflag[tid] = 0; fidx[tid] = -1;
    }
    if (tid == 0) oany = 0;

    // ---- stage: float4 loads along t (128B/d-group), scalar LDS writes ----
    {
        const int t4  = (lane & 7) * 4;
        const int dof = lane >> 3;
        #pragma unroll
        for (int it = 0; it < 8; ++it) {
            int d = (it * NW + w) * 8 + dof;
            float4 v = *reinterpret_cast<const float4*>(xb + (long)d * TT + t4);
            xsf[(t4 + 0) * XLD + d] = v.x;
            xsf[(t4 + 1) * XLD + d] = v.y;
            xsf[(t4 + 2) * XLD + d] = v.z;
            xsf[(t4 + 3) * XLD + d] = v.w;
        }
    }
    __syncthreads();                            // B1: x tile + inits ready

    // ---- GEMM: wave owns 128 codes (8 n-tiles), 2 m-tiles, K=512 ----
    f32x4 acc[2][8];
    #pragma unroll
    for (int m = 0; m < 2; ++m)
        #pragma unroll
        for (int n = 0; n < 8; ++n)
            acc[m][n] = (f32x4){0.f, 0.f, 0.f, 0.f};

    const short8v* Bhv = (const short8v*)Bph;
    {
        const int rl  = lane & 15;
        const int lg8 = (lane >> 4) * 8;
        for (int kk = 0; kk < 16; ++kk) {
            short8v ah[2];
            #pragma unroll
            for (int m = 0; m < 2; ++m)
                ah[m] = build_frag_rm(xsf + (m * 16 + rl) * XLD, kk * 32 + lg8);
            #pragma unroll
            for (int nh = 0; nh < 2; ++nh) {
                short8v bh[4];
                #pragma unroll
                for (int q = 0; q < 4; ++q)
                    bh[q] = Bhv[((w * 8 + nh * 4 + q) * 16 + kk) * 64 + lane];
                __builtin_amdgcn_s_setprio(1);
                #pragma unroll
                for (int q = 0; q < 4; ++q)
                    #pragma unroll
                    for (int m = 0; m < 2; ++m)
                        acc[m][nh * 4 + q] = __builtin_amdgcn_mfma_f32_16x16x32_bf16(
                            ah[m], bh[q], acc[m][nh * 4 + q], 0, 0, 0);
                __builtin_amdgcn_s_setprio(0);
            }
        }
    }

    // ---- epilogue: per-row wave-min -> LDS atomicMin(sortable) || pw ----
    float sef[8];
    #pragma unroll
    for (int n = 0; n < 8; ++n) sef[n] = se[w * 128 + n * 16 + (lane & 15)];

    #pragma unroll
    for (int m = 0; m < 2; ++m) {
        #pragma unroll
        for (int r4 = 0; r4 < 4; ++r4) {
            float mn = 1e30f;
            #pragma unroll
            for (int n = 0; n < 8; ++n)
                mn = fminf(mn, fmaf(-2.f, acc[m][n][r4], sef[n]));
            #pragma unroll
            for (int off = 1; off < 16; off <<= 1)
                mn = fminf(mn, __shfl_xor(mn, off, 64));
            if ((lane & 15) == 0)
                atomicMin(&rowmin[m * 16 + (lane >> 4) * 4 + r4], f2sort(mn));
        }
    }
    {   // pw: r = tid>>4 (32 rows x 16 threads), r12-verified numerics
        int r = tid >> 4, l = tid & 15;
        const float* bp = xsf + r * XLD;
        float pblk[4];
        #pragma unroll
        for (int kb = 0; kb < 4; ++kb) {
            float q[8];
            #pragma unroll
            for (int k = 0; k < 8; ++k) {
                float e = bp[kb * 128 + l + 16 * k];
                q[k] = __fmul_rn(e, e);
            }
            float V = __fadd_rn(__fadd_rn(__fadd_rn(q[0], q[1]), __fadd_rn(q[2], q[3])),
                                __fadd_rn(__fadd_rn(q[4], q[5]), __fadd_rn(q[6], q[7])));
            V = __fadd_rn(V, __shfl_xor(V, 8, 16));
            V = __fadd_rn(V, __shfl_xor(V, 4, 16));
            V = __fadd_rn(V, __shfl_xor(V, 2, 16));
            V = __fadd_rn(V, __shfl_xor(V, 1, 16));
            pblk[kb] = V;
        }
        if (l == 0)
            sxs[r] = __fadd_rn(__fadd_rn(pblk[0], pblk[1]), __fadd_rn(pblk[2], pblk[3]));
    }
    __syncthreads();                            // B2: rowmin + sxs final

    // ---- push candidates within margin (threshold read inline) ----
    #pragma unroll
    for (int m = 0; m < 2; ++m) {
        #pragma unroll
        for (int r4 = 0; r4 < 4; ++r4) {
            int row = m * 16 + (lane >> 4) * 4 + r4;
            float th = sort2f(rowmin[row]) + MARGIN;
            #pragma unroll
            for (int n = 0; n < 8; ++n) {
                float sc = fmaf(-2.f, acc[m][n][r4], sef[n]);
                if (sc <= th) {
                    int pos = atomicAdd(&rcnt[row], 1);
                    if (pos < CM)
                        rc[row][pos] = (unsigned short)(w * 128 + n * 16 + (lane & 15));
                }
            }
        }
    }
    __syncthreads();                            // B3: rc/rcnt final

    // ---- exact fp32 replay: static (row,slot) -> thread map, no pair list ----
    if (lane < 24) {
        int s = lane * 8 + w;                   // 0..191 spread across waves
        int r = s / CM, ci = s - r * CM;
        int cnt = rcnt[r];
        if (cnt >= 2 && cnt <= CM && ci < cnt) {
            int c = (int)rc[r][ci];
            const float4* Ep4 = reinterpret_cast<const float4*>(E + (long)c * DD);
            const float4* Xp4 = reinterpret_cast<const float4*>(xsf + r * XLD);
            float g = 0.f;
            #pragma unroll 4
            for (int jj = 0; jj < 128; ++jj) {
                float4 e4 = Ep4[jj], x4 = Xp4[jj];
                g = __fmaf_rn(x4.x, e4.x, g);   // exact numpy order
                g = __fmaf_rn(x4.y, e4.y, g);
                g = __fmaf_rn(x4.z, e4.z, g);
                g = __fmaf_rn(x4.w, e4.w, g);
            }
            float t1 = __fadd_rn(sxs[r], se[c]);
            float d  = __fsub_rn(t1, __fmul_rn(2.f, g));
            unsigned long long key = ((unsigned long long)f2sort(d) << 10) | (unsigned int)c;
            atomicMin(&rmin[r], key);           // ties -> lower index (numpy)
        }
    }
    __syncthreads();                            // B4: rmin final

    // ---- resolve fidx ----
    if (tid < RWS) {
        int cnt = rcnt[tid];
        if (cnt == 1)                   fidx[tid] = (int)rc[tid][0];
        else if (cnt >= 2 && cnt <= CM) fidx[tid] = (int)(rmin[tid] & 0x3ffu);
        else { oflag[tid] = 1; atomicOr(&oany, 1); }   // overflow (or impossible 0)
    }
    __syncthreads();                            // B5: fidx / oany visible

    // ---- overflow fallback (rare): 2 codes/thread full replay ----
    if (oany) {
        for (int r = 0; r < RWS; ++r) {
            if (!oflag[r]) continue;            // LDS-uniform branch
            const float4* Xp4 = reinterpret_cast<const float4*>(xsf + r * XLD);
            float bd = 1e30f; int bi = KK;
            #pragma unroll
            for (int q = 0; q < 2; ++q) {
                int c = q * BT + tid;           // ascending c => strict < keeps lowest
                const float4* Ep4 = reinterpret_cast<const float4*>(E + (long)c * DD);
                float g = 0.f;
                #pragma unroll 4
                for (int jj = 0; jj < 128; ++jj) {
                    float4 e4 = Ep4[jj], x4 = Xp4[jj];
                    g = __fmaf_rn(x4.x, e4.x, g);
                    g = __fmaf_rn(x4.y, e4.y, g);
                    g = __fmaf_rn(x4.z, e4.z, g);
                    g = __fmaf_rn(x4.w, e4.w, g);
                }
                float d = __fsub_rn(__fadd_rn(sxs[r], se[c]), __fmul_rn(2.f, g));
                if (d < bd) { bd = d; bi = c; }
            }
            #pragma unroll
            for (int off = 32; off; off >>= 1) {
                float tv = __shfl_down(bd, off, 64);
                int   ti = __shfl_down(bi, off, 64);
                if (tv < bd || (tv == bd && ti < bi)) { bd = tv; bi = ti; }
            }
            if (lane == 0) {
                unsigned long long key = ((unsigned long long)f2sort(bd) << 10) | (unsigned int)bi;
                atomicMin(&rmin[r], key);
            }
            __syncthreads();
            if (tid == 0) fidx[r] = (int)(rmin[r] & 0x3ffu);
            __syncthreads();
        }
    }
    __syncthreads();                            // B6: fidx final everywhere

    if (tid < RWS)
        out[(size_t)NN * DD + 1 + nbase + tid] = (float)fidx[tid];

    // ---- gather rows, quantized_st = fl(x + fl(q-x)), fp64 loss ----
    double lacc = 0.0;
    #pragma unroll
    for (int it = 0; it < 8; ++it) {
        int flat = it * BT + tid;               // 4096 float4 = 32 rows * 128
        int r = flat >> 7;
        int j = (flat & 127) * 4;
        int idx = fidx[r];
        float4 ev = *reinterpret_cast<const float4*>(E + (long)idx * DD + j);
        float4 xv = *reinterpret_cast<const float4*>(&xsf[r * XLD + j]);
        float d0 = __fsub_rn(ev.x, xv.x);
        float d1 = __fsub_rn(ev.y, xv.y);
        float d2 = __fsub_rn(ev.z, xv.z);
        float d3 = __fsub_rn(ev.w, xv.w);
        float4 st;
        st.x = __fadd_rn(xv.x, d0); st.y = __fadd_rn(xv.y, d1);
        st.z = __fadd_rn(xv.z, d2); st.w = __fadd_rn(xv.w, d3);
        *reinterpret_cast<float4*>(out + (size_t)(nbase + r) * DD + j) = st;
        lacc += (double)d0 * d0 + (double)d1 * d1 + (double)d2 * d2 + (double)d3 * d3;
    }
    #pragma unroll
    for (int off = 32; off; off >>= 1) lacc += __shfl_down(lacc, off, 64);
    if (lane == 0) wloss[w] = lacc;
    __syncthreads();
    if (tid == 0) {
        double s = 0.0;
        #pragma unroll
        for (int ww = 0; ww < NW; ++ww) s += wloss[ww];
        partials[blk] = s;                      // plain store, no atomic
    }
}

// ---------------- loss finalize: sum 2048 block partials ----------------
__global__ void finalize_kernel(const double* __restrict__ partials, float* __restrict__ out) {
    __shared__ double sm[16];
    const int tid = threadIdx.x;                // 1024 threads
    const int w = tid >> 6, lane = tid & 63;
    double a = partials[tid] + partials[tid + 1024];
    #pragma unroll
    for (int off = 32; off; off >>= 1) a += __shfl_down(a, off, 64);
    if (lane == 0) sm[w] = a;
    __syncthreads();
    if (tid == 0) {
        double s = 0.0;
        #pragma unroll
        for (int i = 0; i < 16; ++i) s += sm[i];
        out[(size_t)NN * DD] = (float)(1.25 * s / ((double)NN * DD));
    }
}

extern "C" void kernel_launch(void* const* d_in, const int* in_sizes, int n_in,
                              void* d_out, int out_size, void* d_ws, size_t ws_size,
                              hipStream_t stream) {
    const float* x = (const float*)d_in[0];
    const float* E = (const float*)d_in[1];
    float* out = (float*)d_out;
    double* partials = (double*)d_ws;                                   // 16 KB
    float* se = (float*)((char*)d_ws + 32768);                          // 4 KB
    unsigned short* Bph = (unsigned short*)((char*)d_ws + 65536);       // 1 MB

    enorms_exact<<<4, 256, 0, stream>>>(E, se);
    pack_e<<<(KK * DD / 2) / 256, 256, 0, stream>>>(E, Bph);
    vq_fused<<<NPART, BT, 0, stream>>>(x, E, Bph, se, partials, out);
    finalize_kernel<<<1, 1024, 0, stream>>>(partials, out);
}

// Round 16
// 208.175 us; speedup vs baseline: 3.0827x; 1.0176x over previous
//
#include <hip/hip_runtime.h>

#define BB 16
#define DD 512
#define TT 4096
#define KK 1024
#define NN (BB*TT)              // 65536 rows
#define RWS 32                  // rows per block
#define BT 512                  // 8 waves
#define NW 8
#define MARGIN 1e-3f            // candidate margin (req <=8e-4, 25% slack)
#define CM 6                    // candidate slots per row
#define XLD 516                 // floats per x row (2064 B, 16B-aligned)
#define NPART (NN/RWS)          // 2048 partials

typedef __attribute__((ext_vector_type(8))) short short8v;   // 8 bf16
typedef __attribute__((ext_vector_type(4))) float f32x4;

// ---- bf16 helper (RNE) ----
__device__ __forceinline__ unsigned short f2bf(float f) {
    unsigned int u = __float_as_uint(f);
    unsigned int r = (u + 0x7fffu + ((u >> 16) & 1u)) >> 16;
    return (unsigned short)r;
}

// ---- sortable-float mapping (monotone: f1<f2 <=> u1<u2) ----
__device__ __forceinline__ unsigned int f2sort(float f) {
    unsigned int b = __float_as_uint(f);
    return (b & 0x80000000u) ? ~b : (b | 0x80000000u);
}
__device__ __forceinline__ float sort2f(unsigned int u) {
    unsigned int b = (u & 0x80000000u) ? (u & 0x7fffffffu) : ~u;
    return __uint_as_float(b);
}

// ---- numpy pairwise-sum replication (fp32, squares) — verified passing ----
__device__ __forceinline__ float pw128_sq_strided(const float* a, int stride) {
    float V[16];
    #pragma unroll
    for (int l = 0; l < 16; ++l) {
        float q[8];
        #pragma unroll
        for (int k = 0; k < 8; ++k) {
            float e = a[(l + 16 * k) * stride];
            q[k] = __fmul_rn(e, e);
        }
        V[l] = __fadd_rn(__fadd_rn(__fadd_rn(q[0], q[1]), __fadd_rn(q[2], q[3])),
                         __fadd_rn(__fadd_rn(q[4], q[5]), __fadd_rn(q[6], q[7])));
    }
    float u[8];
    #pragma unroll
    for (int l = 0; l < 8; ++l) u[l] = __fadd_rn(V[l], V[l + 8]);
    float v[4];
    #pragma unroll
    for (int l = 0; l < 4; ++l) v[l] = __fadd_rn(u[l], u[l + 4]);
    return __fadd_rn(__fadd_rn(v[0], v[2]), __fadd_rn(v[1], v[3]));
}
__device__ __forceinline__ float pw512_sq_strided(const float* a, int stride) {
    float p0 = pw128_sq_strided(a, stride);
    float p1 = pw128_sq_strided(a + 128 * stride, stride);
    float p2 = pw128_sq_strided(a + 256 * stride, stride);
    float p3 = pw128_sq_strided(a + 384 * stride, stride);
    return __fadd_rn(__fadd_rn(p0, p1), __fadd_rn(p2, p3));
}

// ---------------- exact ||e||^2 per code row ----------------
__global__ void enorms_exact(const float* __restrict__ E, float* __restrict__ se) {
    int i = blockIdx.x * blockDim.x + threadIdx.x;
    if (i < KK) se[i] = pw512_sq_strided(E + (long)i * DD, 1);
}

// ---------------- pack E (hi bf16) into MFMA B-fragment layout (u32 pairs) --
__global__ void pack_e(const float* __restrict__ E, unsigned short* __restrict__ Bph) {
    int i = blockIdx.x * blockDim.x + threadIdx.x;   // 0 .. KK*DD/2-1
    if (i >= KK * DD / 2) return;
    int c = i >> 8;
    int k = (i & 255) * 2;
    float2 v = *reinterpret_cast<const float2*>(E + ((long)c << 9) + k);
    int lane = (c & 15) + ((k >> 3) & 3) * 16;
    int hw = (((c >> 4) * 16 + (k >> 5)) * 64 + lane) * 8 + (k & 7);
    unsigned int pk = (unsigned int)f2bf(v.x) | ((unsigned int)f2bf(v.y) << 16);
    *reinterpret_cast<unsigned int*>(Bph + hw) = pk;
}

// ---- build bf16-hi A fragment from row-major f32 LDS row (r5/r13-verified) ----
__device__ __forceinline__ short8v build_frag_rm(const float* __restrict__ row, int c0) {
    union { short8v v; unsigned int wd[4]; } u;
    float4 a = *reinterpret_cast<const float4*>(row + c0);
    float4 b = *reinterpret_cast<const float4*>(row + c0 + 4);
    asm("v_cvt_pk_bf16_f32 %0, %1, %2" : "=v"(u.wd[0]) : "v"(a.x), "v"(a.y));
    asm("v_cvt_pk_bf16_f32 %0, %1, %2" : "=v"(u.wd[1]) : "v"(a.z), "v"(a.w));
    asm("v_cvt_pk_bf16_f32 %0, %1, %2" : "=v"(u.wd[2]) : "v"(b.x), "v"(b.y));
    asm("v_cvt_pk_bf16_f32 %0, %1, %2" : "=v"(u.wd[3]) : "v"(b.z), "v"(b.w));
    return u.v;
}

// =============== fused (2 blocks/CU, 5 barriers common path) ===============
__global__ __launch_bounds__(BT)
void vq_fused(const float* __restrict__ x, const float* __restrict__ E,
              const unsigned short* __restrict__ Bph,
              const float* __restrict__ se,
              double* __restrict__ partials, float* __restrict__ out) {
    __shared__ __align__(16) float xsf[RWS * XLD];   // 66,048 B row-major [r][d]
    __shared__ unsigned int rowmin[RWS];             // sortable-bits global row min
    __shared__ int   rcnt[RWS];
    __shared__ unsigned short rc[RWS][CM];
    __shared__ unsigned long long rmin[RWS];
    __shared__ float sxs[RWS];
    __shared__ int   fidx[RWS];
    __shared__ int   oflag[RWS];
    __shared__ double wloss[NW];
    __shared__ int   oany;

    const int tid  = threadIdx.x;
    const int w    = tid >> 6;              // 0..7
    const int lane = tid & 63;
    const int blk  = blockIdx.x;
    const int b    = blk >> 7;              // 128 blocks per batch
    const int t0   = (blk & 127) * RWS;
    const long nbase = (long)b * TT + t0;
    const float* xb = x + (long)b * DD * TT + t0;

    if (tid < RWS) {
        rcnt[tid] = 0; rowmin[tid] = 0xFFFFFFFFu; rmin[tid] = ~0ull;
        oflag[tid] = 0; fidx[tid] = -1;
    }
    if (tid == 0) oany = 0;

    // ---- stage (r14-proven): dword loads (lane&31 = row), float4 LDS writes ----
    {
        const int r  = lane & 31;
        const int dh = lane >> 5;           // 0/1
        const float* xbl = xb + r;
        #pragma unroll
        for (int it = 0; it < 4; ++it) {
            int d0 = ((it * NW + w) * 2 + dh) * 8;      // 0..504, step 8
            float v[8];
            #pragma unroll
            for (int jj = 0; jj < 8; ++jj)
                v[jj] = xbl[(long)(d0 + jj) * TT];
            float4 lo = {v[0], v[1], v[2], v[3]};
            float4 hi = {v[4], v[5], v[6], v[7]};
            *reinterpret_cast<float4*>(&xsf[r * XLD + d0])     = lo;
            *reinterpret_cast<float4*>(&xsf[r * XLD + d0 + 4]) = hi;
        }
    }
    __syncthreads();                            // B1: x tile + inits ready

    // ---- GEMM: wave owns 128 codes (8 n-tiles), 2 m-tiles, K=512 ----
    f32x4 acc[2][8];
    #pragma unroll
    for (int m = 0; m < 2; ++m)
        #pragma unroll
        for (int n = 0; n < 8; ++n)
            acc[m][n] = (f32x4){0.f, 0.f, 0.f, 0.f};

    const short8v* Bhv = (const short8v*)Bph;
    {
        const int rl  = lane & 15;
        const int lg8 = (lane >> 4) * 8;
        for (int kk = 0; kk < 16; ++kk) {
            short8v ah[2];
            #pragma unroll
            for (int m = 0; m < 2; ++m)
                ah[m] = build_frag_rm(xsf + (m * 16 + rl) * XLD, kk * 32 + lg8);
            #pragma unroll
            for (int nh = 0; nh < 2; ++nh) {
                short8v bh[4];
                #pragma unroll
                for (int q = 0; q < 4; ++q)
                    bh[q] = Bhv[((w * 8 + nh * 4 + q) * 16 + kk) * 64 + lane];
                __builtin_amdgcn_s_setprio(1);
                #pragma unroll
                for (int q = 0; q < 4; ++q)
                    #pragma unroll
                    for (int m = 0; m < 2; ++m)
                        acc[m][nh * 4 + q] = __builtin_amdgcn_mfma_f32_16x16x32_bf16(
                            ah[m], bh[q], acc[m][nh * 4 + q], 0, 0, 0);
                __builtin_amdgcn_s_setprio(0);
            }
        }
    }

    // ---- epilogue: per-row wave-min -> LDS atomicMin(sortable) || pw ----
    float sef[8];
    #pragma unroll
    for (int n = 0; n < 8; ++n) sef[n] = se[w * 128 + n * 16 + (lane & 15)];

    #pragma unroll
    for (int m = 0; m < 2; ++m) {
        #pragma unroll
        for (int r4 = 0; r4 < 4; ++r4) {
            float mn = 1e30f;
            #pragma unroll
            for (int n = 0; n < 8; ++n)
                mn = fminf(mn, fmaf(-2.f, acc[m][n][r4], sef[n]));
            #pragma unroll
            for (int off = 1; off < 16; off <<= 1)
                mn = fminf(mn, __shfl_xor(mn, off, 64));
            if ((lane & 15) == 0)
                atomicMin(&rowmin[m * 16 + (lane >> 4) * 4 + r4], f2sort(mn));
        }
    }
    {   // pw: r = tid>>4 (32 rows x 16 threads), r12-verified numerics
        int r = tid >> 4, l = tid & 15;
        const float* bp = xsf + r * XLD;
        float pblk[4];
        #pragma unroll
        for (int kb = 0; kb < 4; ++kb) {
            float q[8];
            #pragma unroll
            for (int k = 0; k < 8; ++k) {
                float e = bp[kb * 128 + l + 16 * k];
                q[k] = __fmul_rn(e, e);
            }
            float V = __fadd_rn(__fadd_rn(__fadd_rn(q[0], q[1]), __fadd_rn(q[2], q[3])),
                                __fadd_rn(__fadd_rn(q[4], q[5]), __fadd_rn(q[6], q[7])));
            V = __fadd_rn(V, __shfl_xor(V, 8, 16));
            V = __fadd_rn(V, __shfl_xor(V, 4, 16));
            V = __fadd_rn(V, __shfl_xor(V, 2, 16));
            V = __fadd_rn(V, __shfl_xor(V, 1, 16));
            pblk[kb] = V;
        }
        if (l == 0)
            sxs[r] = __fadd_rn(__fadd_rn(pblk[0], pblk[1]), __fadd_rn(pblk[2], pblk[3]));
    }
    __syncthreads();                            // B2: rowmin + sxs final

    // ---- push candidates within margin (threshold read inline) ----
    #pragma unroll
    for (int m = 0; m < 2; ++m) {
        #pragma unroll
        for (int r4 = 0; r4 < 4; ++r4) {
            int row = m * 16 + (lane >> 4) * 4 + r4;
            float th = sort2f(rowmin[row]) + MARGIN;
            #pragma unroll
            for (int n = 0; n < 8; ++n) {
                float sc = fmaf(-2.f, acc[m][n][r4], sef[n]);
                if (sc <= th) {
                    int pos = atomicAdd(&rcnt[row], 1);
                    if (pos < CM)
                        rc[row][pos] = (unsigned short)(w * 128 + n * 16 + (lane & 15));
                }
            }
        }
    }
    __syncthreads();                            // B3: rc/rcnt final

    // ---- exact fp32 replay: static (row,slot) -> thread map, no pair list ----
    if (lane < 24) {
        int s = lane * 8 + w;                   // 0..191 spread across waves
        int r = s / CM, ci = s - r * CM;
        int cnt = rcnt[r];
        if (cnt >= 2 && cnt <= CM && ci < cnt) {
            int c = (int)rc[r][ci];
            const float4* Ep4 = reinterpret_cast<const float4*>(E + (long)c * DD);
            const float4* Xp4 = reinterpret_cast<const float4*>(xsf + r * XLD);
            float g = 0.f;
            #pragma unroll 4
            for (int jj = 0; jj < 128; ++jj) {
                float4 e4 = Ep4[jj], x4 = Xp4[jj];
                g = __fmaf_rn(x4.x, e4.x, g);   // exact numpy order
                g = __fmaf_rn(x4.y, e4.y, g);
                g = __fmaf_rn(x4.z, e4.z, g);
                g = __fmaf_rn(x4.w, e4.w, g);
            }
            float t1 = __fadd_rn(sxs[r], se[c]);
            float d  = __fsub_rn(t1, __fmul_rn(2.f, g));
            unsigned long long key = ((unsigned long long)f2sort(d) << 10) | (unsigned int)c;
            atomicMin(&rmin[r], key);           // ties -> lower index (numpy)
        }
    }
    __syncthreads();                            // B4: rmin final

    // ---- resolve fidx ----
    if (tid < RWS) {
        int cnt = rcnt[tid];
        if (cnt == 1)                   fidx[tid] = (int)rc[tid][0];
        else if (cnt >= 2 && cnt <= CM) fidx[tid] = (int)(rmin[tid] & 0x3ffu);
        else { oflag[tid] = 1; atomicOr(&oany, 1); }   // overflow (or impossible 0)
    }
    __syncthreads();                            // B5: fidx / oany visible

    // ---- overflow fallback (rare, uniform branch): 2 codes/thread replay ----
    if (oany) {
        for (int r = 0; r < RWS; ++r) {
            if (!oflag[r]) continue;            // LDS-uniform branch
            const float4* Xp4 = reinterpret_cast<const float4*>(xsf + r * XLD);
            float bd = 1e30f; int bi = KK;
            #pragma unroll
            for (int q = 0; q < 2; ++q) {
                int c = q * BT + tid;           // ascending c => strict < keeps lowest
                const float4* Ep4 = reinterpret_cast<const float4*>(E + (long)c * DD);
                float g = 0.f;
                #pragma unroll 4
                for (int jj = 0; jj < 128; ++jj) {
                    float4 e4 = Ep4[jj], x4 = Xp4[jj];
                    g = __fmaf_rn(x4.x, e4.x, g);
                    g = __fmaf_rn(x4.y, e4.y, g);
                    g = __fmaf_rn(x4.z, e4.z, g);
                    g = __fmaf_rn(x4.w, e4.w, g);
                }
                float d = __fsub_rn(__fadd_rn(sxs[r], se[c]), __fmul_rn(2.f, g));
                if (d < bd) { bd = d; bi = c; }
            }
            #pragma unroll
            for (int off = 32; off; off >>= 1) {
                float tv = __shfl_down(bd, off, 64);
                int   ti = __shfl_down(bi, off, 64);
                if (tv < bd || (tv == bd && ti < bi)) { bd = tv; bi = ti; }
            }
            if (lane == 0) {
                unsigned long long key = ((unsigned long long)f2sort(bd) << 10) | (unsigned int)bi;
                atomicMin(&rmin[r], key);
            }
            __syncthreads();
            if (tid == 0) fidx[r] = (int)(rmin[r] & 0x3ffu);
            __syncthreads();
        }
        __syncthreads();                        // publish overflow fidx
    }

    if (tid < RWS)
        out[(size_t)NN * DD + 1 + nbase + tid] = (float)fidx[tid];

    // ---- gather rows, quantized_st = fl(x + fl(q-x)), f32 loss accum ----
    float lacc = 0.f;
    #pragma unroll
    for (int it = 0; it < 8; ++it) {
        int flat = it * BT + tid;               // 4096 float4 = 32 rows * 128
        int r = flat >> 7;
        int j = (flat & 127) * 4;
        int idx = fidx[r];
        float4 ev = *reinterpret_cast<const float4*>(E + (long)idx * DD + j);
        float4 xv = *reinterpret_cast<const float4*>(&xsf[r * XLD + j]);
        float d0 = __fsub_rn(ev.x, xv.x);
        float d1 = __fsub_rn(ev.y, xv.y);
        float d2 = __fsub_rn(ev.z, xv.z);
        float d3 = __fsub_rn(ev.w, xv.w);
        float4 st;
        st.x = __fadd_rn(xv.x, d0); st.y = __fadd_rn(xv.y, d1);
        st.z = __fadd_rn(xv.z, d2); st.w = __fadd_rn(xv.w, d3);
        *reinterpret_cast<float4*>(out + (size_t)(nbase + r) * DD + j) = st;
        lacc = __fmaf_rn(d0, d0, lacc);
        lacc = __fmaf_rn(d1, d1, lacc);
        lacc = __fmaf_rn(d2, d2, lacc);
        lacc = __fmaf_rn(d3, d3, lacc);
    }
    double dl = (double)lacc;
    #pragma unroll
    for (int off = 32; off; off >>= 1) dl += __shfl_down(dl, off, 64);
    if (lane == 0) wloss[w] = dl;
    __syncthreads();
    if (tid == 0) {
        double s = 0.0;
        #pragma unroll
        for (int ww = 0; ww < NW; ++ww) s += wloss[ww];
        partials[blk] = s;                      // plain store, no atomic
    }
}

// ---------------- loss finalize: sum 2048 block partials ----------------
__global__ void finalize_kernel(const double* __restrict__ partials, float* __restrict__ out) {
    __shared__ double sm[16];
    const int tid = threadIdx.x;                // 1024 threads
    const int w = tid >> 6, lane = tid & 63;
    double a = partials[tid] + partials[tid + 1024];
    #pragma unroll
    for (int off = 32; off; off >>= 1) a += __shfl_down(a, off, 64);
    if (lane == 0) sm[w] = a;
    __syncthreads();
    if (tid == 0) {
        double s = 0.0;
        #pragma unroll
        for (int i = 0; i < 16; ++i) s += sm[i];
        out[(size_t)NN * DD] = (float)(1.25 * s / ((double)NN * DD));
    }
}

extern "C" void kernel_launch(void* const* d_in, const int* in_sizes, int n_in,
                              void* d_out, int out_size, void* d_ws, size_t ws_size,
                              hipStream_t stream) {
    const float* x = (const float*)d_in[0];
    const float* E = (const float*)d_in[1];
    float* out = (float*)d_out;
    double* partials = (double*)d_ws;                                   // 16 KB
    float* se = (float*)((char*)d_ws + 32768);                          // 4 KB
    unsigned short* Bph = (unsigned short*)((char*)d_ws + 65536);       // 1 MB

    enorms_exact<<<4, 256, 0, stream>>>(E, se);
    pack_e<<<(KK * DD / 2) / 256, 256, 0, stream>>>(E, Bph);
    vq_fused<<<NPART, BT, 0, stream>>>(x, E, Bph, se, partials, out);
    finalize_kernel<<<1, 1024, 0, stream>>>(partials, out);
}